// Round 3
// baseline (2618.640 us; speedup 1.0000x reference)
//
#include <hip/hip_runtime.h>
#include <stdint.h>

#define B_    2
#define SEQ   2048
#define HID   2048
#define NK_   16
#define NV_   32
#define DK_   128
#define DV_   128
#define NQKVZ 12288
#define CONVD 8192
#define MTOT  (B_*SEQ)   // 4096
#define SPLIT 4          // dv-split of recurrence blocks

typedef unsigned short ushort_t;
typedef __bf16 bf16x8 __attribute__((ext_vector_type(8)));
typedef float  f32x4  __attribute__((ext_vector_type(4)));
typedef unsigned short us4 __attribute__((ext_vector_type(4)));

__device__ __forceinline__ ushort_t f2bf(float f){
  union { float f; unsigned u; } v; v.f = f;
  unsigned r = v.u + 0x7FFFu + ((v.u >> 16) & 1u);
  return (ushort_t)(r >> 16);
}
__device__ __forceinline__ float bf2f(ushort_t u){
  union { unsigned u; float f; } v; v.u = ((unsigned)u) << 16; return v.f;
}
__device__ __forceinline__ float sigmoidf_(float x){ return 1.f/(1.f+__expf(-x)); }
__device__ __forceinline__ float siluf_(float x){ return x*sigmoidf_(x); }

// ---------------- cast x -> bf16 ----------------
__global__ void cast_x_kernel(const float* __restrict__ x, ushort_t* __restrict__ xb, int n4){
  int i = blockIdx.x*256 + threadIdx.x;
  if (i >= n4) return;
  float4 v = ((const float4*)x)[i];
  us4 o; o[0]=f2bf(v.x); o[1]=f2bf(v.y); o[2]=f2bf(v.z); o[3]=f2bf(v.w);
  ((us4*)xb)[i] = o;
}

// ---------------- transpose + cast W[K][N] -> Wt[N][K] bf16 ----------------
__global__ __launch_bounds__(256) void transpose_cast(const float* __restrict__ W, ushort_t* __restrict__ Wt,
                                                      int K, int N){
  __shared__ float tile[64][65];
  int n0 = blockIdx.x*64, k0 = blockIdx.y*64;
  int tx = threadIdx.x & 63, ty = threadIdx.x >> 6; // ty 0..3
  #pragma unroll
  for (int i=0;i<16;i++){
    int kr = ty + i*4;
    tile[kr][tx] = W[(size_t)(k0+kr)*N + n0+tx];
  }
  __syncthreads();
  #pragma unroll
  for (int i=0;i<16;i++){
    int nr = ty + i*4;
    Wt[(size_t)(n0+nr)*K + k0+tx] = f2bf(tile[tx][nr]);
  }
}

// ---------------- bf16 MFMA GEMM: C[M][N] = A[M][K] * Bt[N][K]^T ----------------
// OUTBF=1: write bf16, OUTBF=0: write fp32
template<int OUTBF>
__global__ __launch_bounds__(256) void gemm_bf16(const ushort_t* __restrict__ A, const ushort_t* __restrict__ Bt,
                                                 void* __restrict__ Cv, int M, int N, int K){
  __shared__ ushort_t As[128][40];
  __shared__ ushort_t Bs[128][40];
  const int t = threadIdx.x;
  const int lane = t & 63, wid = t >> 6;
  const int wm = wid >> 1, wn = wid & 1;
  const int m0 = blockIdx.y * 128, n0 = blockIdx.x * 128;
  f32x4 acc[4][4];
  #pragma unroll
  for (int i=0;i<4;i++)
    #pragma unroll
    for (int j=0;j<4;j++) acc[i][j] = (f32x4){0.f,0.f,0.f,0.f};
  const int sr = t >> 2;          // 0..63
  const int sk = (t & 3) * 8;     // 0,8,16,24
  for (int k0 = 0; k0 < K; k0 += 32){
    #pragma unroll
    for (int p=0;p<2;p++){
      int r = p*64 + sr;
      *(uint4*)&As[r][sk] = *(const uint4*)&A[(size_t)(m0+r)*K + k0 + sk];
      *(uint4*)&Bs[r][sk] = *(const uint4*)&Bt[(size_t)(n0+r)*K + k0 + sk];
    }
    __syncthreads();
    const int lr = lane & 15, lk = (lane >> 4) * 8;
    bf16x8 af[4], bfv[4];
    #pragma unroll
    for (int i=0;i<4;i++) af[i]  = *(const bf16x8*)&As[wm*64 + i*16 + lr][lk];
    #pragma unroll
    for (int j=0;j<4;j++) bfv[j] = *(const bf16x8*)&Bs[wn*64 + j*16 + lr][lk];
    #pragma unroll
    for (int i=0;i<4;i++)
      #pragma unroll
      for (int j=0;j<4;j++)
        acc[i][j] = __builtin_amdgcn_mfma_f32_16x16x32_bf16(af[i], bfv[j], acc[i][j], 0, 0, 0);
    __syncthreads();
  }
  const int lr = lane & 15, lg = lane >> 4;
  #pragma unroll
  for (int i=0;i<4;i++)
    #pragma unroll
    for (int j=0;j<4;j++)
      #pragma unroll
      for (int r=0;r<4;r++){
        int m = m0 + wm*64 + i*16 + lg*4 + r;
        int n = n0 + wn*64 + j*16 + lr;
        if (OUTBF) ((ushort_t*)Cv)[(size_t)m*N + n] = f2bf(acc[i][j][r]);
        else       ((float*)Cv)[(size_t)m*N + n]    = acc[i][j][r];
      }
}

// ---------------- ba = x @ W_ba (fp32, N=64) ----------------
__global__ __launch_bounds__(256) void gemm_ba(const float* __restrict__ x, const float* __restrict__ Wba,
                                               float* __restrict__ ba){
  int lane = threadIdx.x & 63;
  int wid  = threadIdx.x >> 6;
  int row  = blockIdx.x*4 + wid;
  const float* xr = x + (size_t)row*HID;
  float acc = 0.f;
  for (int k=0;k<HID;k+=4){
    float4 xv = *(const float4*)&xr[k];
    acc += xv.x * Wba[(size_t)(k+0)*64 + lane];
    acc += xv.y * Wba[(size_t)(k+1)*64 + lane];
    acc += xv.z * Wba[(size_t)(k+2)*64 + lane];
    acc += xv.w * Wba[(size_t)(k+3)*64 + lane];
  }
  ba[(size_t)row*64 + lane] = acc;
}

// ---------------- conv(k=4) + SiLU + q/k RMS-norm (bf16 in/out) ----------------
__global__ __launch_bounds__(128) void conv_norm_kernel(const ushort_t* __restrict__ qkvz, const float* __restrict__ conv_w,
                                                        ushort_t* __restrict__ qkv){
  __shared__ float red[2];
  const int blk = blockIdx.x;
  const int gi = blk & 63;
  const int bt = blk >> 6;      // 0..4095
  const int ts = bt & (SEQ-1);
  const int dk = threadIdx.x;
  int col;
  if (gi < 16)       col = gi*768 + dk;
  else if (gi < 32)  col = (gi-16)*768 + 128 + dk;
  else { int nv = gi-32; col = (nv>>1)*768 + 256 + (nv&1)*128 + dk; }
  const int c = gi*128 + dk;
  const float4 w = *(const float4*)&conv_w[(size_t)c*4];
  float a0 = (ts>=3) ? bf2f(qkvz[(size_t)(bt-3)*NQKVZ + col]) : 0.f;
  float a1 = (ts>=2) ? bf2f(qkvz[(size_t)(bt-2)*NQKVZ + col]) : 0.f;
  float a2 = (ts>=1) ? bf2f(qkvz[(size_t)(bt-1)*NQKVZ + col]) : 0.f;
  float a3 =           bf2f(qkvz[(size_t)(bt  )*NQKVZ + col]);
  float acc = a0*w.x + a1*w.y + a2*w.z + a3*w.w;
  float y = siluf_(acc);
  float outv = y;
  if (gi < 32){
    float ss = y*y;
    #pragma unroll
    for (int o=1;o<64;o<<=1) ss += __shfl_xor(ss, o);
    if ((threadIdx.x & 63) == 0) red[threadIdx.x>>6] = ss;
    __syncthreads();
    float tot = red[0] + red[1];
    float rs = rsqrtf(tot*(1.f/128.f) + 1e-6f);
    float scale = (gi < 16) ? (1.f/128.f) : 0.08838834764831845f; // 1/128 , 1/sqrt(128)
    outv = y*rs*scale;
  }
  qkv[(size_t)bt*CONVD + gi*128 + dk] = f2bf(outv);
}

// ---------------- eg = exp(g), beta ----------------
__global__ void gbeta_kernel(const float* __restrict__ ba, const float* __restrict__ A_log,
                             const float* __restrict__ dt_bias, float* __restrict__ egv, float* __restrict__ beta){
  int idx = blockIdx.x*256 + threadIdx.x;
  if (idx >= MTOT*NV_) return;
  int nv = idx & 31;
  int bt = idx >> 5;
  int nk = nv >> 1, r = nv & 1;
  float bg = ba[(size_t)bt*64 + nk*4 + r];
  float ag = ba[(size_t)bt*64 + nk*4 + 2 + r];
  float ad = ag + dt_bias[nv];
  float sp = fmaxf(ad, 0.f) + log1pf(__expf(-fabsf(ad)));
  float g  = -__expf(A_log[nv]) * sp;
  egv[idx]  = __expf(g);
  beta[idx] = sigmoidf_(bg);
}

// ---------------- gated delta-rule recurrence ----------------
// grid = 64 heads * SPLIT; block 256 threads.
// thread t: dkg = t&7 (16-dk block), dvl = t>>3 (dv within this block's 32-dv slice)
__global__ __launch_bounds__(256) void recurrence_kernel(const ushort_t* __restrict__ qkv, const float* __restrict__ egv,
                                                         const float* __restrict__ betav, float* __restrict__ outc){
  const int bi = blockIdx.x;            // [0, 64*SPLIT)
  const int b  = bi >> 7;               // 128 blocks per batch
  const int nv = (bi >> 2) & 31;
  const int sp = bi & 3;
  const int nk = nv >> 1;
  const int t  = threadIdx.x;
  const int dkg = t & 7;
  const int dvl = t >> 3;
  float4 S[4];
  #pragma unroll
  for (int j=0;j<4;j++) S[j] = (float4){0.f,0.f,0.f,0.f};
  __shared__ float stg[2][288];   // [0,128)=k  [128,256)=q  [256,288)=v slice

  const bool active = (t < 144);
  const int e = t*2;
  int col = 0;
  if (active){
    if (e < 128)       col = 2048 + nk*128 + e;
    else if (e < 256)  col = nk*128 + (e-128);
    else               col = 4096 + nv*128 + sp*32 + (e-256);
  }
  const size_t bt0 = (size_t)b*SEQ;

  // prologue: stage ts=0
  ushort2 nx = make_ushort2(0,0);
  if (active) nx = *(const ushort2*)&qkv[bt0*CONVD + col];
  float eg_c = egv[bt0*NV_ + nv];
  float bt_c = betav[bt0*NV_ + nv];
  if (active){ stg[0][e] = bf2f(nx.x); stg[0][e+1] = bf2f(nx.y); }
  __syncthreads();
  int cur = 0;

  for (int ts=0; ts<SEQ; ++ts){
    const size_t bt = bt0 + ts;
    // prefetch ts+1
    float eg_n = 0.f, bt_n = 0.f;
    if (ts+1 < SEQ){
      if (active) nx = *(const ushort2*)&qkv[(bt+1)*CONVD + col];
      eg_n = egv[(bt+1)*NV_ + nv];
      bt_n = betav[(bt+1)*NV_ + nv];
    }
    // compute from stg[cur]
    const float4* kk = (const float4*)&stg[cur][dkg*16];
    const float4* qq = (const float4*)&stg[cur][128 + dkg*16];
    const float vv = stg[cur][256 + dvl];
    float4 kr[4];
    float kvp0=0.f, kvp1=0.f, kvp2=0.f, kvp3=0.f;
    {
      float4 k4, s;
      k4 = kk[0]; kr[0]=k4; s = S[0]; s.x*=eg_c; s.y*=eg_c; s.z*=eg_c; s.w*=eg_c; S[0]=s;
      kvp0 = k4.x*s.x + k4.y*s.y + k4.z*s.z + k4.w*s.w;
      k4 = kk[1]; kr[1]=k4; s = S[1]; s.x*=eg_c; s.y*=eg_c; s.z*=eg_c; s.w*=eg_c; S[1]=s;
      kvp1 = k4.x*s.x + k4.y*s.y + k4.z*s.z + k4.w*s.w;
      k4 = kk[2]; kr[2]=k4; s = S[2]; s.x*=eg_c; s.y*=eg_c; s.z*=eg_c; s.w*=eg_c; S[2]=s;
      kvp2 = k4.x*s.x + k4.y*s.y + k4.z*s.z + k4.w*s.w;
      k4 = kk[3]; kr[3]=k4; s = S[3]; s.x*=eg_c; s.y*=eg_c; s.z*=eg_c; s.w*=eg_c; S[3]=s;
      kvp3 = k4.x*s.x + k4.y*s.y + k4.z*s.z + k4.w*s.w;
    }
    float kv = (kvp0+kvp1)+(kvp2+kvp3);
    kv += __shfl_xor(kv, 1); kv += __shfl_xor(kv, 2); kv += __shfl_xor(kv, 4);
    const float d = (vv - kv) * bt_c;
    float op0=0.f, op1=0.f, op2=0.f, op3=0.f;
    {
      float4 s, k4, q4;
      k4=kr[0]; q4=qq[0]; s=S[0];
      s.x += k4.x*d; s.y += k4.y*d; s.z += k4.z*d; s.w += k4.w*d; S[0]=s;
      op0 = q4.x*s.x + q4.y*s.y + q4.z*s.z + q4.w*s.w;
      k4=kr[1]; q4=qq[1]; s=S[1];
      s.x += k4.x*d; s.y += k4.y*d; s.z += k4.z*d; s.w += k4.w*d; S[1]=s;
      op1 = q4.x*s.x + q4.y*s.y + q4.z*s.z + q4.w*s.w;
      k4=kr[2]; q4=qq[2]; s=S[2];
      s.x += k4.x*d; s.y += k4.y*d; s.z += k4.z*d; s.w += k4.w*d; S[2]=s;
      op2 = q4.x*s.x + q4.y*s.y + q4.z*s.z + q4.w*s.w;
      k4=kr[3]; q4=qq[3]; s=S[3];
      s.x += k4.x*d; s.y += k4.y*d; s.z += k4.z*d; s.w += k4.w*d; S[3]=s;
      op3 = q4.x*s.x + q4.y*s.y + q4.z*s.z + q4.w*s.w;
    }
    float o = (op0+op1)+(op2+op3);
    o += __shfl_xor(o, 1); o += __shfl_xor(o, 2); o += __shfl_xor(o, 4);
    if (dkg == 0)
      outc[(bt*NV_ + nv)*(size_t)DV_ + sp*32 + dvl] = o;
    // stage ts+1 into the other buffer
    if (ts+1 < SEQ && active){
      stg[cur^1][e]   = bf2f(nx.x);
      stg[cur^1][e+1] = bf2f(nx.y);
    }
    __syncthreads();
    cur ^= 1; eg_c = eg_n; bt_c = bt_n;
  }
}

// ---------------- gated RMSNorm -> bf16 ----------------
__global__ __launch_bounds__(128) void gatenorm_kernel(const float* __restrict__ outc, const ushort_t* __restrict__ qkvz,
                                                       const float* __restrict__ norm_w, ushort_t* __restrict__ gated){
  __shared__ float red[2];
  const int blk = blockIdx.x;
  const int nv = blk & 31;
  const size_t bt = (size_t)(blk >> 5);
  const int dv = threadIdx.x;
  float xv = outc[(bt*NV_ + nv)*(size_t)DV_ + dv];
  float ss = xv*xv;
  #pragma unroll
  for (int o=1;o<64;o<<=1) ss += __shfl_xor(ss, o);
  if ((threadIdx.x & 63)==0) red[threadIdx.x>>6] = ss;
  __syncthreads();
  float tot = red[0]+red[1];
  float xn = xv * rsqrtf(tot*(1.f/128.f) + 1e-6f) * norm_w[dv];
  int nk = nv>>1, r = nv&1;
  float z = bf2f(qkvz[bt*NQKVZ + nk*768 + 512 + r*128 + dv]);
  gated[bt*(size_t)4096 + nv*128 + dv] = f2bf(siluf_(z)*xn);
}

extern "C" void kernel_launch(void* const* d_in, const int* in_sizes, int n_in,
                              void* d_out, int out_size, void* d_ws, size_t ws_size,
                              hipStream_t stream){
  (void)in_sizes; (void)n_in; (void)out_size; (void)ws_size;
  const float* x      = (const float*)d_in[0];
  const float* W_qkvz = (const float*)d_in[1];
  const float* W_ba   = (const float*)d_in[2];
  const float* conv_w = (const float*)d_in[3];
  const float* dt_bias= (const float*)d_in[4];
  const float* A_log  = (const float*)d_in[5];
  const float* norm_w = (const float*)d_in[6];
  const float* W_out  = (const float*)d_in[7];
  float* outp = (float*)d_out;

  // ---- workspace layout (237 MB total, aggressively aliased) ----
  char* w = (char*)d_ws;
  const size_t R0 = 0;                         // qkvz bf16: 100,663,296
  const size_t R1 = 100663296;                 // xb(16.8M)+wqt(50.3M) -> qkv bf16(67.1M) -> gated bf16(33.6M)
  const size_t R2 = R1 + 67108864;             // core fp32 (67.1M) -> wot bf16(16.8M)
  const size_t R3 = R2 + 67108864;             // smalls
  ushort_t* qkvz_bf = (ushort_t*)(w + R0);
  ushort_t* xb      = (ushort_t*)(w + R1);
  ushort_t* wqt     = (ushort_t*)(w + R1 + 16777216);
  ushort_t* qkv_bf  = (ushort_t*)(w + R1);
  ushort_t* gated   = (ushort_t*)(w + R1);
  float*    core    = (float*)   (w + R2);
  ushort_t* wot     = (ushort_t*)(w + R2);
  float*    ba      = (float*)   (w + R3);
  float*    egv     = (float*)   (w + R3 + 1048576);
  float*    betav   = (float*)   (w + R3 + 1572864);

  cast_x_kernel<<<(MTOT*HID/4 + 255)/256, 256, 0, stream>>>(x, xb, MTOT*HID/4);
  transpose_cast<<<dim3(NQKVZ/64, HID/64), 256, 0, stream>>>(W_qkvz, wqt, HID, NQKVZ);
  gemm_bf16<1><<<dim3(NQKVZ/128, MTOT/128), 256, 0, stream>>>(xb, wqt, (void*)qkvz_bf, MTOT, NQKVZ, HID);
  gemm_ba<<<MTOT/4, 256, 0, stream>>>(x, W_ba, ba);
  gbeta_kernel<<<(MTOT*NV_+255)/256, 256, 0, stream>>>(ba, A_log, dt_bias, egv, betav);
  conv_norm_kernel<<<MTOT*64, 128, 0, stream>>>(qkvz_bf, conv_w, qkv_bf);
  recurrence_kernel<<<64*SPLIT, 256, 0, stream>>>(qkv_bf, egv, betav, core);
  gatenorm_kernel<<<MTOT*NV_, 128, 0, stream>>>(core, qkvz_bf, norm_w, gated);
  transpose_cast<<<dim3(2048/64, 4096/64), 256, 0, stream>>>(W_out, wot, 4096, 2048);
  gemm_bf16<0><<<dim3(2048/128, MTOT/128), 256, 0, stream>>>(gated, wot, (void*)outp, MTOT, 2048, 4096);
}

// Round 4
// 1915.918 us; speedup vs baseline: 1.3668x; 1.3668x over previous
//
#include <hip/hip_runtime.h>
#include <stdint.h>

#define B_    2
#define SEQ   2048
#define HID   2048
#define NK_   16
#define NV_   32
#define DK_   128
#define DV_   128
#define NQKVZ 12288
#define CONVD 8192
#define MTOT  (B_*SEQ)   // 4096
#define SPLIT 4          // dv-split of recurrence blocks

typedef unsigned short ushort_t;
typedef __bf16 bf16x8 __attribute__((ext_vector_type(8)));
typedef float  f32x4  __attribute__((ext_vector_type(4)));
typedef unsigned short us4 __attribute__((ext_vector_type(4)));

__device__ __forceinline__ ushort_t f2bf(float f){
  union { float f; unsigned u; } v; v.f = f;
  unsigned r = v.u + 0x7FFFu + ((v.u >> 16) & 1u);
  return (ushort_t)(r >> 16);
}
__device__ __forceinline__ float bf2f(ushort_t u){
  union { unsigned u; float f; } v; v.u = ((unsigned)u) << 16; return v.f;
}
__device__ __forceinline__ float bflo(unsigned u){
  union { unsigned x; float f; } v; v.x = u << 16; return v.f;
}
__device__ __forceinline__ float bfhi(unsigned u){
  union { unsigned x; float f; } v; v.x = u & 0xffff0000u; return v.f;
}
__device__ __forceinline__ float dot4(f32x4 a, f32x4 b){
  return a[0]*b[0] + a[1]*b[1] + a[2]*b[2] + a[3]*b[3];
}
__device__ __forceinline__ float sigmoidf_(float x){ return 1.f/(1.f+__expf(-x)); }
__device__ __forceinline__ float siluf_(float x){ return x*sigmoidf_(x); }

// unpack uint4 (8 bf16, memory order) -> two f32x4
#define UNPK(u, f0, f1) \
  f0 = (f32x4){bflo(u.x), bfhi(u.x), bflo(u.y), bfhi(u.y)}; \
  f1 = (f32x4){bflo(u.z), bfhi(u.z), bflo(u.w), bfhi(u.w)};

// ---------------- cast x -> bf16 ----------------
__global__ void cast_x_kernel(const float* __restrict__ x, ushort_t* __restrict__ xb, int n4){
  int i = blockIdx.x*256 + threadIdx.x;
  if (i >= n4) return;
  float4 v = ((const float4*)x)[i];
  us4 o; o[0]=f2bf(v.x); o[1]=f2bf(v.y); o[2]=f2bf(v.z); o[3]=f2bf(v.w);
  ((us4*)xb)[i] = o;
}

// ---------------- transpose + cast W[K][N] -> Wt[N][K] bf16 ----------------
__global__ __launch_bounds__(256) void transpose_cast(const float* __restrict__ W, ushort_t* __restrict__ Wt,
                                                      int K, int N){
  __shared__ float tile[64][65];
  int n0 = blockIdx.x*64, k0 = blockIdx.y*64;
  int tx = threadIdx.x & 63, ty = threadIdx.x >> 6; // ty 0..3
  #pragma unroll
  for (int i=0;i<16;i++){
    int kr = ty + i*4;
    tile[kr][tx] = W[(size_t)(k0+kr)*N + n0+tx];
  }
  __syncthreads();
  #pragma unroll
  for (int i=0;i<16;i++){
    int nr = ty + i*4;
    Wt[(size_t)(n0+nr)*K + k0+tx] = f2bf(tile[tx][nr]);
  }
}

// ---------------- bf16 MFMA GEMM (m97-style global_load_lds staging) ----------------
// C[M][N] = A[M][K] * Bt[N][K]^T ; OUTBF=1: bf16 out, 0: fp32 out
template<int OUTBF>
__global__ __launch_bounds__(256) void gemm_bf16(const ushort_t* __restrict__ A, const ushort_t* __restrict__ Bt,
                                                 void* __restrict__ Cv, int M, int N, int K){
  __shared__ ushort_t As[128][32];   // unpadded: required by global_load_lds (linear dest)
  __shared__ ushort_t Bs[128][32];
  const int t = threadIdx.x;
  const int lane = t & 63, w = t >> 6;
  const int wm = w >> 1, wn = w & 1;
  const int m0 = blockIdx.y * 128, n0 = blockIdx.x * 128;
  // staging: wave w covers rows [w*16, w*16+16) and [64+w*16, ...); lane l -> row l>>2, 16B chunk l&3
  const int srow = lane >> 2;
  const int scol = (lane & 3) * 8;
  const ushort_t* gA0 = &A [(size_t)(m0 +      w*16 + srow)*K + scol];
  const ushort_t* gA1 = &A [(size_t)(m0 + 64 + w*16 + srow)*K + scol];
  const ushort_t* gB0 = &Bt[(size_t)(n0 +      w*16 + srow)*K + scol];
  const ushort_t* gB1 = &Bt[(size_t)(n0 + 64 + w*16 + srow)*K + scol];
  ushort_t* lA0 = &As[     w*16][0];   // wave-uniform LDS bases; HW adds lane*16B
  ushort_t* lA1 = &As[64 + w*16][0];
  ushort_t* lB0 = &Bs[     w*16][0];
  ushort_t* lB1 = &Bs[64 + w*16][0];
  f32x4 acc[4][4];
  #pragma unroll
  for (int i=0;i<4;i++)
    #pragma unroll
    for (int j=0;j<4;j++) acc[i][j] = (f32x4){0.f,0.f,0.f,0.f};
  const int lr = lane & 15, lk = (lane >> 4) * 8;
  for (int k0 = 0; k0 < K; k0 += 32){
    __builtin_amdgcn_global_load_lds((const __attribute__((address_space(1))) void*)(gA0 + k0),
                                     (__attribute__((address_space(3))) void*)lA0, 16, 0, 0);
    __builtin_amdgcn_global_load_lds((const __attribute__((address_space(1))) void*)(gA1 + k0),
                                     (__attribute__((address_space(3))) void*)lA1, 16, 0, 0);
    __builtin_amdgcn_global_load_lds((const __attribute__((address_space(1))) void*)(gB0 + k0),
                                     (__attribute__((address_space(3))) void*)lB0, 16, 0, 0);
    __builtin_amdgcn_global_load_lds((const __attribute__((address_space(1))) void*)(gB1 + k0),
                                     (__attribute__((address_space(3))) void*)lB1, 16, 0, 0);
    __syncthreads();   // compiler emits s_waitcnt vmcnt(0) before barrier -> LDS ready
    bf16x8 af[4], bfv[4];
    #pragma unroll
    for (int i=0;i<4;i++) af[i]  = *(const bf16x8*)&As[wm*64 + i*16 + lr][lk];
    #pragma unroll
    for (int j=0;j<4;j++) bfv[j] = *(const bf16x8*)&Bs[wn*64 + j*16 + lr][lk];
    #pragma unroll
    for (int i=0;i<4;i++)
      #pragma unroll
      for (int j=0;j<4;j++)
        acc[i][j] = __builtin_amdgcn_mfma_f32_16x16x32_bf16(af[i], bfv[j], acc[i][j], 0, 0, 0);
    __syncthreads();
  }
  const int lg = lane >> 4;
  #pragma unroll
  for (int i=0;i<4;i++)
    #pragma unroll
    for (int j=0;j<4;j++)
      #pragma unroll
      for (int r=0;r<4;r++){
        int m = m0 + wm*64 + i*16 + lg*4 + r;
        int n = n0 + wn*64 + j*16 + lr;
        if (OUTBF) ((ushort_t*)Cv)[(size_t)m*N + n] = f2bf(acc[i][j][r]);
        else       ((float*)Cv)[(size_t)m*N + n]    = acc[i][j][r];
      }
}

// ---------------- ba = x @ W_ba (fp32, N=64) ----------------
__global__ __launch_bounds__(256) void gemm_ba(const float* __restrict__ x, const float* __restrict__ Wba,
                                               float* __restrict__ ba){
  int lane = threadIdx.x & 63;
  int wid  = threadIdx.x >> 6;
  int row  = blockIdx.x*4 + wid;
  const float* xr = x + (size_t)row*HID;
  float acc = 0.f;
  for (int k=0;k<HID;k+=4){
    float4 xv = *(const float4*)&xr[k];
    acc += xv.x * Wba[(size_t)(k+0)*64 + lane];
    acc += xv.y * Wba[(size_t)(k+1)*64 + lane];
    acc += xv.z * Wba[(size_t)(k+2)*64 + lane];
    acc += xv.w * Wba[(size_t)(k+3)*64 + lane];
  }
  ba[(size_t)row*64 + lane] = acc;
}

// ---------------- conv(k=4) + SiLU + q/k RMS-norm (bf16 in/out) ----------------
__global__ __launch_bounds__(128) void conv_norm_kernel(const ushort_t* __restrict__ qkvz, const float* __restrict__ conv_w,
                                                        ushort_t* __restrict__ qkv){
  __shared__ float red[2];
  const int blk = blockIdx.x;
  const int gi = blk & 63;
  const int bt = blk >> 6;      // 0..4095
  const int ts = bt & (SEQ-1);
  const int dk = threadIdx.x;
  int col;
  if (gi < 16)       col = gi*768 + dk;
  else if (gi < 32)  col = (gi-16)*768 + 128 + dk;
  else { int nv = gi-32; col = (nv>>1)*768 + 256 + (nv&1)*128 + dk; }
  const int c = gi*128 + dk;
  const float4 w = *(const float4*)&conv_w[(size_t)c*4];
  float a0 = (ts>=3) ? bf2f(qkvz[(size_t)(bt-3)*NQKVZ + col]) : 0.f;
  float a1 = (ts>=2) ? bf2f(qkvz[(size_t)(bt-2)*NQKVZ + col]) : 0.f;
  float a2 = (ts>=1) ? bf2f(qkvz[(size_t)(bt-1)*NQKVZ + col]) : 0.f;
  float a3 =           bf2f(qkvz[(size_t)(bt  )*NQKVZ + col]);
  float acc = a0*w.x + a1*w.y + a2*w.z + a3*w.w;
  float y = siluf_(acc);
  float outv = y;
  if (gi < 32){
    float ss = y*y;
    #pragma unroll
    for (int o=1;o<64;o<<=1) ss += __shfl_xor(ss, o);
    if ((threadIdx.x & 63) == 0) red[threadIdx.x>>6] = ss;
    __syncthreads();
    float tot = red[0] + red[1];
    float rs = rsqrtf(tot*(1.f/128.f) + 1e-6f);
    float scale = (gi < 16) ? (1.f/128.f) : 0.08838834764831845f; // 1/128 , 1/sqrt(128)
    outv = y*rs*scale;
  }
  qkv[(size_t)bt*CONVD + gi*128 + dk] = f2bf(outv);
}

// ---------------- {exp(g), beta} as float2 ----------------
__global__ void gbeta_kernel(const float* __restrict__ ba, const float* __restrict__ A_log,
                             const float* __restrict__ dt_bias, float2* __restrict__ egb){
  int idx = blockIdx.x*256 + threadIdx.x;
  if (idx >= MTOT*NV_) return;
  int nv = idx & 31;
  int bt = idx >> 5;
  int nk = nv >> 1, r = nv & 1;
  float bg = ba[(size_t)bt*64 + nk*4 + r];
  float ag = ba[(size_t)bt*64 + nk*4 + 2 + r];
  float ad = ag + dt_bias[nv];
  float sp = fmaxf(ad, 0.f) + log1pf(__expf(-fabsf(ad)));
  float g  = -__expf(A_log[nv]) * sp;
  egb[idx] = make_float2(__expf(g), sigmoidf_(bg));
}

// ---------------- gated delta-rule recurrence (barrier-free, register-resident) ----------------
// grid = 64 heads * SPLIT; block 256 = 4 independent waves; no LDS, no __syncthreads.
// thread t: dkg = t&7 (16-dk slice), dvl = t>>3 (dv column in this block's 32-dv slice)
__global__ __launch_bounds__(256) void recurrence_kernel(const ushort_t* __restrict__ qkv,
                                                         const float2* __restrict__ egb,
                                                         float* __restrict__ outc){
  const int bi = blockIdx.x;            // [0, 64*SPLIT)
  const int b  = bi >> 7;
  const int nv = (bi >> 2) & 31;
  const int sp = bi & 3;
  const int nk = nv >> 1;
  const int t  = threadIdx.x;
  const int dkg = t & 7;
  const int dvl = t >> 3;               // 0..31
  const size_t bt0 = (size_t)b*SEQ;
  const ushort_t* kp = qkv + bt0*CONVD + 2048 + nk*128 + dkg*16;
  const ushort_t* qp = qkv + bt0*CONVD +        nk*128 + dkg*16;
  const ushort_t* vp = qkv + bt0*CONVD + 4096 + nv*128 + sp*32 + dvl;
  const float2*   ep = egb + bt0*NV_ + nv;
  float*          op = outc + (bt0*NV_ + nv)*(size_t)DV_ + sp*32 + dvl;

  f32x4 S0 = {0.f,0.f,0.f,0.f}, S1 = S0, S2 = S0, S3 = S0;

  auto load = [&](int ts, uint4& ku0, uint4& ku1, uint4& qu0, uint4& qu1, ushort_t& v, float2& eb){
    const size_t roff = (size_t)ts*CONVD;
    const uint4* k4 = (const uint4*)(kp + roff);
    ku0 = k4[0]; ku1 = k4[1];
    const uint4* q4 = (const uint4*)(qp + roff);
    qu0 = q4[0]; qu1 = q4[1];
    v  = vp[roff];
    eb = ep[(size_t)ts*NV_];
  };

  auto step = [&](const uint4& ku0, const uint4& ku1, const uint4& qu0, const uint4& qu1,
                  ushort_t vus, float2 eb, int ts){
    f32x4 k0,k1,k2,k3,q0,q1,q2,q3;
    UNPK(ku0,k0,k1) UNPK(ku1,k2,k3)
    UNPK(qu0,q0,q1) UNPK(qu1,q2,q3)
    const float eg = eb.x, be = eb.y;
    S0 *= eg; S1 *= eg; S2 *= eg; S3 *= eg;
    float kv = dot4(k0,S0) + dot4(k1,S1) + dot4(k2,S2) + dot4(k3,S3);
    kv += __shfl_xor(kv,1); kv += __shfl_xor(kv,2); kv += __shfl_xor(kv,4);
    const float d = (bf2f(vus) - kv) * be;
    S0 += k0*d; S1 += k1*d; S2 += k2*d; S3 += k3*d;
    float o = dot4(q0,S0) + dot4(q1,S1) + dot4(q2,S2) + dot4(q3,S3);
    o += __shfl_xor(o,1); o += __shfl_xor(o,2); o += __shfl_xor(o,4);
    if (dkg == 0) op[(size_t)ts*(NV_*DV_)] = o;
  };

  // 4-buffer software pipeline (~3 steps of prefetch depth to cover HBM/L2 latency)
  uint4 a0,a1,a2,a3; ushort_t av; float2 ae;
  uint4 b0,b1,b2,b3; ushort_t bv; float2 bev;
  uint4 c0,c1,c2,c3; ushort_t cv; float2 ce;
  uint4 d0,d1,d2,d3; ushort_t dv2; float2 de;
  load(0, a0,a1,a2,a3, av, ae);
  load(1, b0,b1,b2,b3, bv, bev);
  load(2, c0,c1,c2,c3, cv, ce);
  for (int ts=0; ts<SEQ; ts+=4){
    load(ts+3, d0,d1,d2,d3, dv2, de);
    step(a0,a1,a2,a3, av, ae, ts);
    int n4 = (ts+4 < SEQ) ? ts+4 : SEQ-1;
    load(n4, a0,a1,a2,a3, av, ae);
    step(b0,b1,b2,b3, bv, bev, ts+1);
    int n5 = (ts+5 < SEQ) ? ts+5 : SEQ-1;
    load(n5, b0,b1,b2,b3, bv, bev);
    step(c0,c1,c2,c3, cv, ce, ts+2);
    int n6 = (ts+6 < SEQ) ? ts+6 : SEQ-1;
    load(n6, c0,c1,c2,c3, cv, ce);
    step(d0,d1,d2,d3, dv2, de, ts+3);
  }
}

// ---------------- gated RMSNorm -> bf16 ----------------
__global__ __launch_bounds__(128) void gatenorm_kernel(const float* __restrict__ outc, const ushort_t* __restrict__ qkvz,
                                                       const float* __restrict__ norm_w, ushort_t* __restrict__ gated){
  __shared__ float red[2];
  const int blk = blockIdx.x;
  const int nv = blk & 31;
  const size_t bt = (size_t)(blk >> 5);
  const int dv = threadIdx.x;
  float xv = outc[(bt*NV_ + nv)*(size_t)DV_ + dv];
  float ss = xv*xv;
  #pragma unroll
  for (int o=1;o<64;o<<=1) ss += __shfl_xor(ss, o);
  if ((threadIdx.x & 63)==0) red[threadIdx.x>>6] = ss;
  __syncthreads();
  float tot = red[0]+red[1];
  float xn = xv * rsqrtf(tot*(1.f/128.f) + 1e-6f) * norm_w[dv];
  int nk = nv>>1, r = nv&1;
  float z = bf2f(qkvz[bt*NQKVZ + nk*768 + 512 + r*128 + dv]);
  gated[bt*(size_t)4096 + nv*128 + dv] = f2bf(siluf_(z)*xn);
}

extern "C" void kernel_launch(void* const* d_in, const int* in_sizes, int n_in,
                              void* d_out, int out_size, void* d_ws, size_t ws_size,
                              hipStream_t stream){
  (void)in_sizes; (void)n_in; (void)out_size; (void)ws_size;
  const float* x      = (const float*)d_in[0];
  const float* W_qkvz = (const float*)d_in[1];
  const float* W_ba   = (const float*)d_in[2];
  const float* conv_w = (const float*)d_in[3];
  const float* dt_bias= (const float*)d_in[4];
  const float* A_log  = (const float*)d_in[5];
  const float* norm_w = (const float*)d_in[6];
  const float* W_out  = (const float*)d_in[7];
  float* outp = (float*)d_out;

  // ---- workspace layout (~238 MB, aliased; proven size from round 3) ----
  char* w = (char*)d_ws;
  const size_t R0 = 0;                         // qkvz bf16: 100,663,296
  const size_t R1 = 100663296;                 // xb(16.8M)+wqt(50.3M) -> qkv bf16(67.1M) -> gated bf16(33.6M)
  const size_t R2 = R1 + 67108864;             // core fp32 (67.1M) -> wot bf16(16.8M)
  const size_t R3 = R2 + 67108864;             // smalls
  ushort_t* qkvz_bf = (ushort_t*)(w + R0);
  ushort_t* xb      = (ushort_t*)(w + R1);
  ushort_t* wqt     = (ushort_t*)(w + R1 + 16777216);
  ushort_t* qkv_bf  = (ushort_t*)(w + R1);
  ushort_t* gated   = (ushort_t*)(w + R1);
  float*    core    = (float*)   (w + R2);
  ushort_t* wot     = (ushort_t*)(w + R2);
  float*    ba      = (float*)   (w + R3);
  float2*   egb     = (float2*)  (w + R3 + 1048576);

  cast_x_kernel<<<(MTOT*HID/4 + 255)/256, 256, 0, stream>>>(x, xb, MTOT*HID/4);
  transpose_cast<<<dim3(NQKVZ/64, HID/64), 256, 0, stream>>>(W_qkvz, wqt, HID, NQKVZ);
  gemm_bf16<1><<<dim3(NQKVZ/128, MTOT/128), 256, 0, stream>>>(xb, wqt, (void*)qkvz_bf, MTOT, NQKVZ, HID);
  gemm_ba<<<MTOT/4, 256, 0, stream>>>(x, W_ba, ba);
  gbeta_kernel<<<(MTOT*NV_+255)/256, 256, 0, stream>>>(ba, A_log, dt_bias, egb);
  conv_norm_kernel<<<MTOT*64, 128, 0, stream>>>(qkvz_bf, conv_w, qkv_bf);
  recurrence_kernel<<<64*SPLIT, 256, 0, stream>>>(qkv_bf, egb, core);
  gatenorm_kernel<<<MTOT*NV_, 128, 0, stream>>>(core, qkvz_bf, norm_w, gated);
  transpose_cast<<<dim3(2048/64, 4096/64), 256, 0, stream>>>(W_out, wot, 4096, 2048);
  gemm_bf16<0><<<dim3(2048/128, MTOT/128), 256, 0, stream>>>(gated, wot, (void*)outp, MTOT, 2048, 4096);
}

// Round 5
// 1910.666 us; speedup vs baseline: 1.3705x; 1.0027x over previous
//
#include <hip/hip_runtime.h>
#include <stdint.h>

#define B_    2
#define SEQ   2048
#define HID   2048
#define NK_   16
#define NV_   32
#define DK_   128
#define DV_   128
#define NQKVZ 12288
#define CONVD 8192
#define MTOT  (B_*SEQ)   // 4096
#define SPLIT 16         // dv-split of recurrence blocks (8 dv per block)

typedef unsigned short ushort_t;
typedef __bf16 bf16x8 __attribute__((ext_vector_type(8)));
typedef float  f32x4  __attribute__((ext_vector_type(4)));
typedef unsigned short us4 __attribute__((ext_vector_type(4)));

__device__ __forceinline__ ushort_t f2bf(float f){
  union { float f; unsigned u; } v; v.f = f;
  unsigned r = v.u + 0x7FFFu + ((v.u >> 16) & 1u);
  return (ushort_t)(r >> 16);
}
__device__ __forceinline__ float bf2f(ushort_t u){
  union { unsigned u; float f; } v; v.u = ((unsigned)u) << 16; return v.f;
}
__device__ __forceinline__ float bflo(unsigned u){
  union { unsigned x; float f; } v; v.x = u << 16; return v.f;
}
__device__ __forceinline__ float bfhi(unsigned u){
  union { unsigned x; float f; } v; v.x = u & 0xffff0000u; return v.f;
}
__device__ __forceinline__ float dot4(f32x4 a, f32x4 b){
  return a[0]*b[0] + a[1]*b[1] + a[2]*b[2] + a[3]*b[3];
}
__device__ __forceinline__ float sigmoidf_(float x){ return 1.f/(1.f+__expf(-x)); }
__device__ __forceinline__ float siluf_(float x){ return x*sigmoidf_(x); }

// ---------------- cast x -> bf16 ----------------
__global__ void cast_x_kernel(const float* __restrict__ x, ushort_t* __restrict__ xb, int n4){
  int i = blockIdx.x*256 + threadIdx.x;
  if (i >= n4) return;
  float4 v = ((const float4*)x)[i];
  us4 o; o[0]=f2bf(v.x); o[1]=f2bf(v.y); o[2]=f2bf(v.z); o[3]=f2bf(v.w);
  ((us4*)xb)[i] = o;
}

// ---------------- transpose + cast W[K][N] -> Wt[N][K] bf16 ----------------
__global__ __launch_bounds__(256) void transpose_cast(const float* __restrict__ W, ushort_t* __restrict__ Wt,
                                                      int K, int N){
  __shared__ float tile[64][65];
  int n0 = blockIdx.x*64, k0 = blockIdx.y*64;
  int tx = threadIdx.x & 63, ty = threadIdx.x >> 6; // ty 0..3
  #pragma unroll
  for (int i=0;i<16;i++){
    int kr = ty + i*4;
    tile[kr][tx] = W[(size_t)(k0+kr)*N + n0+tx];
  }
  __syncthreads();
  #pragma unroll
  for (int i=0;i<16;i++){
    int nr = ty + i*4;
    Wt[(size_t)(n0+nr)*K + k0+tx] = f2bf(tile[tx][nr]);
  }
}

// ---------------- bf16 MFMA GEMM (global_load_lds staging) ----------------
// C[M][N] = A[M][K] * Bt[N][K]^T ; OUTBF=1: bf16 out, 0: fp32 out
template<int OUTBF>
__global__ __launch_bounds__(256) void gemm_bf16(const ushort_t* __restrict__ A, const ushort_t* __restrict__ Bt,
                                                 void* __restrict__ Cv, int M, int N, int K){
  __shared__ ushort_t As[128][32];   // unpadded: required by global_load_lds (linear dest)
  __shared__ ushort_t Bs[128][32];
  const int t = threadIdx.x;
  const int lane = t & 63, w = t >> 6;
  const int wm = w >> 1, wn = w & 1;
  const int m0 = blockIdx.y * 128, n0 = blockIdx.x * 128;
  const int srow = lane >> 2;
  const int scol = (lane & 3) * 8;
  const ushort_t* gA0 = &A [(size_t)(m0 +      w*16 + srow)*K + scol];
  const ushort_t* gA1 = &A [(size_t)(m0 + 64 + w*16 + srow)*K + scol];
  const ushort_t* gB0 = &Bt[(size_t)(n0 +      w*16 + srow)*K + scol];
  const ushort_t* gB1 = &Bt[(size_t)(n0 + 64 + w*16 + srow)*K + scol];
  ushort_t* lA0 = &As[     w*16][0];
  ushort_t* lA1 = &As[64 + w*16][0];
  ushort_t* lB0 = &Bs[     w*16][0];
  ushort_t* lB1 = &Bs[64 + w*16][0];
  f32x4 acc[4][4];
  #pragma unroll
  for (int i=0;i<4;i++)
    #pragma unroll
    for (int j=0;j<4;j++) acc[i][j] = (f32x4){0.f,0.f,0.f,0.f};
  const int lr = lane & 15, lk = (lane >> 4) * 8;
  for (int k0 = 0; k0 < K; k0 += 32){
    __builtin_amdgcn_global_load_lds((const __attribute__((address_space(1))) void*)(gA0 + k0),
                                     (__attribute__((address_space(3))) void*)lA0, 16, 0, 0);
    __builtin_amdgcn_global_load_lds((const __attribute__((address_space(1))) void*)(gA1 + k0),
                                     (__attribute__((address_space(3))) void*)lA1, 16, 0, 0);
    __builtin_amdgcn_global_load_lds((const __attribute__((address_space(1))) void*)(gB0 + k0),
                                     (__attribute__((address_space(3))) void*)lB0, 16, 0, 0);
    __builtin_amdgcn_global_load_lds((const __attribute__((address_space(1))) void*)(gB1 + k0),
                                     (__attribute__((address_space(3))) void*)lB1, 16, 0, 0);
    __syncthreads();
    bf16x8 af[4], bfv[4];
    #pragma unroll
    for (int i=0;i<4;i++) af[i]  = *(const bf16x8*)&As[wm*64 + i*16 + lr][lk];
    #pragma unroll
    for (int j=0;j<4;j++) bfv[j] = *(const bf16x8*)&Bs[wn*64 + j*16 + lr][lk];
    #pragma unroll
    for (int i=0;i<4;i++)
      #pragma unroll
      for (int j=0;j<4;j++)
        acc[i][j] = __builtin_amdgcn_mfma_f32_16x16x32_bf16(af[i], bfv[j], acc[i][j], 0, 0, 0);
    __syncthreads();
  }
  const int lg = lane >> 4;
  #pragma unroll
  for (int i=0;i<4;i++)
    #pragma unroll
    for (int j=0;j<4;j++)
      #pragma unroll
      for (int r=0;r<4;r++){
        int m = m0 + wm*64 + i*16 + lg*4 + r;
        int n = n0 + wn*64 + j*16 + lr;
        if (OUTBF) ((ushort_t*)Cv)[(size_t)m*N + n] = f2bf(acc[i][j][r]);
        else       ((float*)Cv)[(size_t)m*N + n]    = acc[i][j][r];
      }
}

// ---------------- ba = x @ W_ba (fp32, N=64) ----------------
__global__ __launch_bounds__(256) void gemm_ba(const float* __restrict__ x, const float* __restrict__ Wba,
                                               float* __restrict__ ba){
  int lane = threadIdx.x & 63;
  int wid  = threadIdx.x >> 6;
  int row  = blockIdx.x*4 + wid;
  const float* xr = x + (size_t)row*HID;
  float acc = 0.f;
  for (int k=0;k<HID;k+=4){
    float4 xv = *(const float4*)&xr[k];
    acc += xv.x * Wba[(size_t)(k+0)*64 + lane];
    acc += xv.y * Wba[(size_t)(k+1)*64 + lane];
    acc += xv.z * Wba[(size_t)(k+2)*64 + lane];
    acc += xv.w * Wba[(size_t)(k+3)*64 + lane];
  }
  ba[(size_t)row*64 + lane] = acc;
}

// ---------------- conv(k=4) + SiLU + q/k RMS-norm (bf16 in/out) ----------------
__global__ __launch_bounds__(128) void conv_norm_kernel(const ushort_t* __restrict__ qkvz, const float* __restrict__ conv_w,
                                                        ushort_t* __restrict__ qkv){
  __shared__ float red[2];
  const int blk = blockIdx.x;
  const int gi = blk & 63;
  const int bt = blk >> 6;      // 0..4095
  const int ts = bt & (SEQ-1);
  const int dk = threadIdx.x;
  int col;
  if (gi < 16)       col = gi*768 + dk;
  else if (gi < 32)  col = (gi-16)*768 + 128 + dk;
  else { int nv = gi-32; col = (nv>>1)*768 + 256 + (nv&1)*128 + dk; }
  const int c = gi*128 + dk;
  const float4 w = *(const float4*)&conv_w[(size_t)c*4];
  float a0 = (ts>=3) ? bf2f(qkvz[(size_t)(bt-3)*NQKVZ + col]) : 0.f;
  float a1 = (ts>=2) ? bf2f(qkvz[(size_t)(bt-2)*NQKVZ + col]) : 0.f;
  float a2 = (ts>=1) ? bf2f(qkvz[(size_t)(bt-1)*NQKVZ + col]) : 0.f;
  float a3 =           bf2f(qkvz[(size_t)(bt  )*NQKVZ + col]);
  float acc = a0*w.x + a1*w.y + a2*w.z + a3*w.w;
  float y = siluf_(acc);
  float outv = y;
  if (gi < 32){
    float ss = y*y;
    #pragma unroll
    for (int o=1;o<64;o<<=1) ss += __shfl_xor(ss, o);
    if ((threadIdx.x & 63) == 0) red[threadIdx.x>>6] = ss;
    __syncthreads();
    float tot = red[0] + red[1];
    float rs = rsqrtf(tot*(1.f/128.f) + 1e-6f);
    float scale = (gi < 16) ? (1.f/128.f) : 0.08838834764831845f; // 1/128 , 1/sqrt(128)
    outv = y*rs*scale;
  }
  qkv[(size_t)bt*CONVD + gi*128 + dk] = f2bf(outv);
}

// ---------------- {exp(g), beta} as float2 ----------------
__global__ void gbeta_kernel(const float* __restrict__ ba, const float* __restrict__ A_log,
                             const float* __restrict__ dt_bias, float2* __restrict__ egb){
  int idx = blockIdx.x*256 + threadIdx.x;
  if (idx >= MTOT*NV_) return;
  int nv = idx & 31;
  int bt = idx >> 5;
  int nk = nv >> 1, r = nv & 1;
  float bg = ba[(size_t)bt*64 + nk*4 + r];
  float ag = ba[(size_t)bt*64 + nk*4 + 2 + r];
  float ad = ag + dt_bias[nv];
  float sp = fmaxf(ad, 0.f) + log1pf(__expf(-fabsf(ad)));
  float g  = -__expf(A_log[nv]) * sp;
  egb[idx] = make_float2(__expf(g), sigmoidf_(bg));
}

// ---------------- gated delta-rule recurrence (barrier-free, register-resident) ----------------
// grid = 64 heads * SPLIT(16); block 256 = 4 independent waves; no LDS, no __syncthreads.
// thread t: dkg = t&31 (4-dk slice), dvl = t>>5 (dv column in this block's 8-dv slice)
__global__ __launch_bounds__(256) void recurrence_kernel(const ushort_t* __restrict__ qkv,
                                                         const float2* __restrict__ egb,
                                                         float* __restrict__ outc){
  const int bi = blockIdx.x;            // [0, 64*SPLIT)
  const int b  = bi >> 9;               // 512 blocks per batch
  const int nv = (bi >> 4) & 31;
  const int sp = bi & 15;
  const int nk = nv >> 1;
  const int t  = threadIdx.x;
  const int dkg = t & 31;               // 4-dk slice
  const int dvl = t >> 5;               // 0..7
  const size_t bt0 = (size_t)b*SEQ;
  const ushort_t* kp = qkv + bt0*CONVD + 2048 + nk*128 + dkg*4;
  const ushort_t* qp = qkv + bt0*CONVD +        nk*128 + dkg*4;
  const ushort_t* vp = qkv + bt0*CONVD + 4096 + nv*128 + sp*8 + dvl;
  const float2*   ep = egb + bt0*NV_ + nv;
  float*          op = outc + (bt0*NV_ + nv)*(size_t)DV_ + sp*8 + dvl;

  f32x4 S = {0.f,0.f,0.f,0.f};

  auto load = [&](int ts, uint2& ku, uint2& qu, ushort_t& v, float2& eb){
    const size_t roff = (size_t)ts*CONVD;
    ku = *(const uint2*)(kp + roff);
    qu = *(const uint2*)(qp + roff);
    v  = vp[roff];
    eb = ep[(size_t)ts*NV_];
  };

  auto step = [&](uint2 ku, uint2 qu, ushort_t vus, float2 eb, int ts){
    f32x4 k = {bflo(ku.x), bfhi(ku.x), bflo(ku.y), bfhi(ku.y)};
    f32x4 q = {bflo(qu.x), bfhi(qu.x), bflo(qu.y), bfhi(qu.y)};
    const float eg = eb.x, be = eb.y;
    S *= eg;
    float kv = dot4(k, S);
    kv += __shfl_xor(kv,1); kv += __shfl_xor(kv,2); kv += __shfl_xor(kv,4);
    kv += __shfl_xor(kv,8); kv += __shfl_xor(kv,16);
    const float d = (bf2f(vus) - kv) * be;
    S += k*d;
    float o = dot4(q, S);
    o += __shfl_xor(o,1); o += __shfl_xor(o,2); o += __shfl_xor(o,4);
    o += __shfl_xor(o,8); o += __shfl_xor(o,16);
    if (dkg == 0) op[(size_t)ts*(NV_*DV_)] = o;
  };

  // 4-buffer software pipeline (~3 steps of prefetch depth to cover L2/HBM latency)
  uint2 a0,a1; ushort_t av; float2 ae;
  uint2 b0,b1; ushort_t bv; float2 be2;
  uint2 c0,c1; ushort_t cv; float2 ce;
  uint2 d0,d1; ushort_t dv2; float2 de;
  load(0, a0,a1, av, ae);
  load(1, b0,b1, bv, be2);
  load(2, c0,c1, cv, ce);
  for (int ts=0; ts<SEQ; ts+=4){
    load(ts+3, d0,d1, dv2, de);
    step(a0,a1, av, ae, ts);
    int n4 = (ts+4 < SEQ) ? ts+4 : SEQ-1;
    load(n4, a0,a1, av, ae);
    step(b0,b1, bv, be2, ts+1);
    int n5 = (ts+5 < SEQ) ? ts+5 : SEQ-1;
    load(n5, b0,b1, bv, be2);
    step(c0,c1, cv, ce, ts+2);
    int n6 = (ts+6 < SEQ) ? ts+6 : SEQ-1;
    load(n6, c0,c1, cv, ce);
    step(d0,d1, dv2, de, ts+3);
  }
}

// ---------------- gated RMSNorm -> bf16 ----------------
__global__ __launch_bounds__(128) void gatenorm_kernel(const float* __restrict__ outc, const ushort_t* __restrict__ qkvz,
                                                       const float* __restrict__ norm_w, ushort_t* __restrict__ gated){
  __shared__ float red[2];
  const int blk = blockIdx.x;
  const int nv = blk & 31;
  const size_t bt = (size_t)(blk >> 5);
  const int dv = threadIdx.x;
  float xv = outc[(bt*NV_ + nv)*(size_t)DV_ + dv];
  float ss = xv*xv;
  #pragma unroll
  for (int o=1;o<64;o<<=1) ss += __shfl_xor(ss, o);
  if ((threadIdx.x & 63)==0) red[threadIdx.x>>6] = ss;
  __syncthreads();
  float tot = red[0]+red[1];
  float xn = xv * rsqrtf(tot*(1.f/128.f) + 1e-6f) * norm_w[dv];
  int nk = nv>>1, r = nv&1;
  float z = bf2f(qkvz[bt*NQKVZ + nk*768 + 512 + r*128 + dv]);
  gated[bt*(size_t)4096 + nv*128 + dv] = f2bf(siluf_(z)*xn);
}

extern "C" void kernel_launch(void* const* d_in, const int* in_sizes, int n_in,
                              void* d_out, int out_size, void* d_ws, size_t ws_size,
                              hipStream_t stream){
  (void)in_sizes; (void)n_in; (void)out_size; (void)ws_size;
  const float* x      = (const float*)d_in[0];
  const float* W_qkvz = (const float*)d_in[1];
  const float* W_ba   = (const float*)d_in[2];
  const float* conv_w = (const float*)d_in[3];
  const float* dt_bias= (const float*)d_in[4];
  const float* A_log  = (const float*)d_in[5];
  const float* norm_w = (const float*)d_in[6];
  const float* W_out  = (const float*)d_in[7];
  float* outp = (float*)d_out;

  // ---- workspace layout (~238 MB, aliased; proven from round 3/4) ----
  char* w = (char*)d_ws;
  const size_t R0 = 0;                         // qkvz bf16: 100,663,296
  const size_t R1 = 100663296;                 // xb(16.8M)+wqt(50.3M) -> qkv bf16(67.1M) -> gated bf16(33.6M)
  const size_t R2 = R1 + 67108864;             // core fp32 (67.1M) -> wot bf16(16.8M)
  const size_t R3 = R2 + 67108864;             // smalls
  ushort_t* qkvz_bf = (ushort_t*)(w + R0);
  ushort_t* xb      = (ushort_t*)(w + R1);
  ushort_t* wqt     = (ushort_t*)(w + R1 + 16777216);
  ushort_t* qkv_bf  = (ushort_t*)(w + R1);
  ushort_t* gated   = (ushort_t*)(w + R1);
  float*    core    = (float*)   (w + R2);
  ushort_t* wot     = (ushort_t*)(w + R2);
  float*    ba      = (float*)   (w + R3);
  float2*   egb     = (float2*)  (w + R3 + 1048576);

  cast_x_kernel<<<(MTOT*HID/4 + 255)/256, 256, 0, stream>>>(x, xb, MTOT*HID/4);
  transpose_cast<<<dim3(NQKVZ/64, HID/64), 256, 0, stream>>>(W_qkvz, wqt, HID, NQKVZ);
  gemm_bf16<1><<<dim3(NQKVZ/128, MTOT/128), 256, 0, stream>>>(xb, wqt, (void*)qkvz_bf, MTOT, NQKVZ, HID);
  gemm_ba<<<MTOT/4, 256, 0, stream>>>(x, W_ba, ba);
  gbeta_kernel<<<(MTOT*NV_+255)/256, 256, 0, stream>>>(ba, A_log, dt_bias, egb);
  conv_norm_kernel<<<MTOT*64, 128, 0, stream>>>(qkvz_bf, conv_w, qkv_bf);
  recurrence_kernel<<<64*SPLIT, 256, 0, stream>>>(qkv_bf, egb, core);
  gatenorm_kernel<<<MTOT*NV_, 128, 0, stream>>>(core, qkvz_bf, norm_w, gated);
  transpose_cast<<<dim3(2048/64, 4096/64), 256, 0, stream>>>(W_out, wot, 4096, 2048);
  gemm_bf16<0><<<dim3(2048/128, MTOT/128), 256, 0, stream>>>(gated, wot, (void*)outp, MTOT, 2048, 4096);
}

// Round 6
// 1286.061 us; speedup vs baseline: 2.0362x; 1.4857x over previous
//
#include <hip/hip_runtime.h>
#include <stdint.h>

#define B_    2
#define SEQ   2048
#define HID   2048
#define NK_   16
#define NV_   32
#define DK_   128
#define DV_   128
#define NQKVZ 12288
#define CONVD 8192
#define MTOT  (B_*SEQ)   // 4096
#define SPLIT 8          // dv-split of recurrence blocks (16 dv per block)

typedef unsigned short ushort_t;
typedef __bf16 bf16x8 __attribute__((ext_vector_type(8)));
typedef float  f32x4  __attribute__((ext_vector_type(4)));
typedef unsigned short us4 __attribute__((ext_vector_type(4)));

__device__ __forceinline__ ushort_t f2bf(float f){
  union { float f; unsigned u; } v; v.f = f;
  unsigned r = v.u + 0x7FFFu + ((v.u >> 16) & 1u);
  return (ushort_t)(r >> 16);
}
__device__ __forceinline__ float bf2f(ushort_t u){
  union { unsigned u; float f; } v; v.u = ((unsigned)u) << 16; return v.f;
}
__device__ __forceinline__ float bflo(unsigned u){
  union { unsigned x; float f; } v; v.x = u << 16; return v.f;
}
__device__ __forceinline__ float bfhi(unsigned u){
  union { unsigned x; float f; } v; v.x = u & 0xffff0000u; return v.f;
}
__device__ __forceinline__ float dot4(f32x4 a, f32x4 b){
  return a[0]*b[0] + a[1]*b[1] + a[2]*b[2] + a[3]*b[3];
}
__device__ __forceinline__ float sigmoidf_(float x){ return 1.f/(1.f+__expf(-x)); }
__device__ __forceinline__ float siluf_(float x){ return x*sigmoidf_(x); }

// sum across the 16 lanes of a DPP row via rotate-adds (pure VALU, no DS pipe).
// After ror 1,2,4,8 every lane in the row holds the full 16-lane sum.
__device__ __forceinline__ float rowsum16(float x){
  int m;
  m = __builtin_amdgcn_update_dpp(0, __float_as_int(x), 0x121, 0xF, 0xF, true); x += __int_as_float(m); // row_ror:1
  m = __builtin_amdgcn_update_dpp(0, __float_as_int(x), 0x122, 0xF, 0xF, true); x += __int_as_float(m); // row_ror:2
  m = __builtin_amdgcn_update_dpp(0, __float_as_int(x), 0x124, 0xF, 0xF, true); x += __int_as_float(m); // row_ror:4
  m = __builtin_amdgcn_update_dpp(0, __float_as_int(x), 0x128, 0xF, 0xF, true); x += __int_as_float(m); // row_ror:8
  return x;
}

// unpack uint4 (8 bf16, memory order) -> two f32x4
#define UNPK(u, f0, f1) \
  f0 = (f32x4){bflo(u.x), bfhi(u.x), bflo(u.y), bfhi(u.y)}; \
  f1 = (f32x4){bflo(u.z), bfhi(u.z), bflo(u.w), bfhi(u.w)};

// ---------------- cast x -> bf16 ----------------
__global__ void cast_x_kernel(const float* __restrict__ x, ushort_t* __restrict__ xb, int n4){
  int i = blockIdx.x*256 + threadIdx.x;
  if (i >= n4) return;
  float4 v = ((const float4*)x)[i];
  us4 o; o[0]=f2bf(v.x); o[1]=f2bf(v.y); o[2]=f2bf(v.z); o[3]=f2bf(v.w);
  ((us4*)xb)[i] = o;
}

// ---------------- transpose + cast W[K][N] -> Wt[N][K] bf16 ----------------
__global__ __launch_bounds__(256) void transpose_cast(const float* __restrict__ W, ushort_t* __restrict__ Wt,
                                                      int K, int N){
  __shared__ float tile[64][65];
  int n0 = blockIdx.x*64, k0 = blockIdx.y*64;
  int tx = threadIdx.x & 63, ty = threadIdx.x >> 6; // ty 0..3
  #pragma unroll
  for (int i=0;i<16;i++){
    int kr = ty + i*4;
    tile[kr][tx] = W[(size_t)(k0+kr)*N + n0+tx];
  }
  __syncthreads();
  #pragma unroll
  for (int i=0;i<16;i++){
    int nr = ty + i*4;
    Wt[(size_t)(n0+nr)*K + k0+tx] = f2bf(tile[tx][nr]);
  }
}

// ---------------- bf16 MFMA GEMM (global_load_lds staging) ----------------
// C[M][N] = A[M][K] * Bt[N][K]^T ; OUTBF=1: bf16 out, 0: fp32 out
template<int OUTBF>
__global__ __launch_bounds__(256) void gemm_bf16(const ushort_t* __restrict__ A, const ushort_t* __restrict__ Bt,
                                                 void* __restrict__ Cv, int M, int N, int K){
  __shared__ ushort_t As[128][32];   // unpadded: required by global_load_lds (linear dest)
  __shared__ ushort_t Bs[128][32];
  const int t = threadIdx.x;
  const int lane = t & 63, w = t >> 6;
  const int wm = w >> 1, wn = w & 1;
  const int m0 = blockIdx.y * 128, n0 = blockIdx.x * 128;
  const int srow = lane >> 2;
  const int scol = (lane & 3) * 8;
  const ushort_t* gA0 = &A [(size_t)(m0 +      w*16 + srow)*K + scol];
  const ushort_t* gA1 = &A [(size_t)(m0 + 64 + w*16 + srow)*K + scol];
  const ushort_t* gB0 = &Bt[(size_t)(n0 +      w*16 + srow)*K + scol];
  const ushort_t* gB1 = &Bt[(size_t)(n0 + 64 + w*16 + srow)*K + scol];
  ushort_t* lA0 = &As[     w*16][0];
  ushort_t* lA1 = &As[64 + w*16][0];
  ushort_t* lB0 = &Bs[     w*16][0];
  ushort_t* lB1 = &Bs[64 + w*16][0];
  f32x4 acc[4][4];
  #pragma unroll
  for (int i=0;i<4;i++)
    #pragma unroll
    for (int j=0;j<4;j++) acc[i][j] = (f32x4){0.f,0.f,0.f,0.f};
  const int lr = lane & 15, lk = (lane >> 4) * 8;
  for (int k0 = 0; k0 < K; k0 += 32){
    __builtin_amdgcn_global_load_lds((const __attribute__((address_space(1))) void*)(gA0 + k0),
                                     (__attribute__((address_space(3))) void*)lA0, 16, 0, 0);
    __builtin_amdgcn_global_load_lds((const __attribute__((address_space(1))) void*)(gA1 + k0),
                                     (__attribute__((address_space(3))) void*)lA1, 16, 0, 0);
    __builtin_amdgcn_global_load_lds((const __attribute__((address_space(1))) void*)(gB0 + k0),
                                     (__attribute__((address_space(3))) void*)lB0, 16, 0, 0);
    __builtin_amdgcn_global_load_lds((const __attribute__((address_space(1))) void*)(gB1 + k0),
                                     (__attribute__((address_space(3))) void*)lB1, 16, 0, 0);
    __syncthreads();
    bf16x8 af[4], bfv[4];
    #pragma unroll
    for (int i=0;i<4;i++) af[i]  = *(const bf16x8*)&As[wm*64 + i*16 + lr][lk];
    #pragma unroll
    for (int j=0;j<4;j++) bfv[j] = *(const bf16x8*)&Bs[wn*64 + j*16 + lr][lk];
    #pragma unroll
    for (int i=0;i<4;i++)
      #pragma unroll
      for (int j=0;j<4;j++)
        acc[i][j] = __builtin_amdgcn_mfma_f32_16x16x32_bf16(af[i], bfv[j], acc[i][j], 0, 0, 0);
    __syncthreads();
  }
  const int lg = lane >> 4;
  #pragma unroll
  for (int i=0;i<4;i++)
    #pragma unroll
    for (int j=0;j<4;j++)
      #pragma unroll
      for (int r=0;r<4;r++){
        int m = m0 + wm*64 + i*16 + lg*4 + r;
        int n = n0 + wn*64 + j*16 + lr;
        if (OUTBF) ((ushort_t*)Cv)[(size_t)m*N + n] = f2bf(acc[i][j][r]);
        else       ((float*)Cv)[(size_t)m*N + n]    = acc[i][j][r];
      }
}

// ---------------- ba = x @ W_ba (fp32, N=64) ----------------
__global__ __launch_bounds__(256) void gemm_ba(const float* __restrict__ x, const float* __restrict__ Wba,
                                               float* __restrict__ ba){
  int lane = threadIdx.x & 63;
  int wid  = threadIdx.x >> 6;
  int row  = blockIdx.x*4 + wid;
  const float* xr = x + (size_t)row*HID;
  float acc = 0.f;
  for (int k=0;k<HID;k+=4){
    float4 xv = *(const float4*)&xr[k];
    acc += xv.x * Wba[(size_t)(k+0)*64 + lane];
    acc += xv.y * Wba[(size_t)(k+1)*64 + lane];
    acc += xv.z * Wba[(size_t)(k+2)*64 + lane];
    acc += xv.w * Wba[(size_t)(k+3)*64 + lane];
  }
  ba[(size_t)row*64 + lane] = acc;
}

// ---------------- conv(k=4) + SiLU + q/k RMS-norm (bf16 in/out) ----------------
__global__ __launch_bounds__(128) void conv_norm_kernel(const ushort_t* __restrict__ qkvz, const float* __restrict__ conv_w,
                                                        ushort_t* __restrict__ qkv){
  __shared__ float red[2];
  const int blk = blockIdx.x;
  const int gi = blk & 63;
  const int bt = blk >> 6;      // 0..4095
  const int ts = bt & (SEQ-1);
  const int dk = threadIdx.x;
  int col;
  if (gi < 16)       col = gi*768 + dk;
  else if (gi < 32)  col = (gi-16)*768 + 128 + dk;
  else { int nv = gi-32; col = (nv>>1)*768 + 256 + (nv&1)*128 + dk; }
  const int c = gi*128 + dk;
  const float4 w = *(const float4*)&conv_w[(size_t)c*4];
  float a0 = (ts>=3) ? bf2f(qkvz[(size_t)(bt-3)*NQKVZ + col]) : 0.f;
  float a1 = (ts>=2) ? bf2f(qkvz[(size_t)(bt-2)*NQKVZ + col]) : 0.f;
  float a2 = (ts>=1) ? bf2f(qkvz[(size_t)(bt-1)*NQKVZ + col]) : 0.f;
  float a3 =           bf2f(qkvz[(size_t)(bt  )*NQKVZ + col]);
  float acc = a0*w.x + a1*w.y + a2*w.z + a3*w.w;
  float y = siluf_(acc);
  float outv = y;
  if (gi < 32){
    float ss = y*y;
    #pragma unroll
    for (int o=1;o<64;o<<=1) ss += __shfl_xor(ss, o);
    if ((threadIdx.x & 63) == 0) red[threadIdx.x>>6] = ss;
    __syncthreads();
    float tot = red[0] + red[1];
    float rs = rsqrtf(tot*(1.f/128.f) + 1e-6f);
    float scale = (gi < 16) ? (1.f/128.f) : 0.08838834764831845f; // 1/128 , 1/sqrt(128)
    outv = y*rs*scale;
  }
  qkv[(size_t)bt*CONVD + gi*128 + dk] = f2bf(outv);
}

// ---------------- {exp(g), beta} as float2 ----------------
__global__ void gbeta_kernel(const float* __restrict__ ba, const float* __restrict__ A_log,
                             const float* __restrict__ dt_bias, float2* __restrict__ egb){
  int idx = blockIdx.x*256 + threadIdx.x;
  if (idx >= MTOT*NV_) return;
  int nv = idx & 31;
  int bt = idx >> 5;
  int nk = nv >> 1, r = nv & 1;
  float bg = ba[(size_t)bt*64 + nk*4 + r];
  float ag = ba[(size_t)bt*64 + nk*4 + 2 + r];
  float ad = ag + dt_bias[nv];
  float sp = fmaxf(ad, 0.f) + log1pf(__expf(-fabsf(ad)));
  float g  = -__expf(A_log[nv]) * sp;
  egb[idx] = make_float2(__expf(g), sigmoidf_(bg));
}

// ---------------- gated delta-rule recurrence (barrier-free, DPP row-reduce) ----------------
// grid = 64 heads * SPLIT(8); block 256 = 4 waves; no LDS, no __syncthreads, no DS crosslane.
// thread t: dkg = t&15 (8-dk slice, one DPP row), dvl = t>>4 (dv column in this block's 16-dv slice)
__global__ __launch_bounds__(256) void recurrence_kernel(const ushort_t* __restrict__ qkv,
                                                         const float2* __restrict__ egb,
                                                         float* __restrict__ outc){
  const int bi = blockIdx.x;            // [0, 64*SPLIT)
  const int b  = bi >> 8;               // 256 blocks per batch
  const int nv = (bi >> 3) & 31;
  const int sp = bi & 7;
  const int nk = nv >> 1;
  const int t  = threadIdx.x;
  const int dkg = t & 15;               // 8-dk slice (lane within DPP row)
  const int dvl = t >> 4;               // 0..15
  const size_t bt0 = (size_t)b*SEQ;
  const ushort_t* kp = qkv + bt0*CONVD + 2048 + nk*128 + dkg*8;
  const ushort_t* qp = qkv + bt0*CONVD +        nk*128 + dkg*8;
  const ushort_t* vp = qkv + bt0*CONVD + 4096 + nv*128 + sp*16 + dvl;
  const float2*   ep = egb + bt0*NV_ + nv;
  float*          op = outc + (bt0*NV_ + nv)*(size_t)DV_ + sp*16 + dvl;

  f32x4 S0 = {0.f,0.f,0.f,0.f}, S1 = {0.f,0.f,0.f,0.f};

  auto load = [&](int ts, uint4& ku, uint4& qu, ushort_t& v, float2& eb){
    const size_t roff = (size_t)ts*CONVD;
    ku = *(const uint4*)(kp + roff);
    qu = *(const uint4*)(qp + roff);
    v  = vp[roff];
    eb = ep[(size_t)ts*NV_];
  };

  auto step = [&](const uint4& ku, const uint4& qu, ushort_t vus, float2 eb, int ts){
    f32x4 k0,k1,q0,q1;
    UNPK(ku,k0,k1)
    UNPK(qu,q0,q1)
    const float eg = eb.x, be = eb.y;
    S0 *= eg; S1 *= eg;
    float kv = dot4(k0,S0) + dot4(k1,S1);
    kv = rowsum16(kv);
    const float d = (bf2f(vus) - kv) * be;
    S0 += k0*d; S1 += k1*d;
    float o = dot4(q0,S0) + dot4(q1,S1);
    o = rowsum16(o);
    if (dkg == 0) op[(size_t)ts*(NV_*DV_)] = o;
  };

  // 4-buffer software pipeline (~3 steps of prefetch depth to cover L2/HBM latency)
  uint4 a0; uint4 a1; ushort_t av; float2 ae;
  uint4 b0; uint4 b1; ushort_t bv; float2 be2;
  uint4 c0; uint4 c1; ushort_t cv; float2 ce;
  uint4 d0; uint4 d1; ushort_t dv2; float2 de;
  load(0, a0,a1, av, ae);
  load(1, b0,b1, bv, be2);
  load(2, c0,c1, cv, ce);
  for (int ts=0; ts<SEQ; ts+=4){
    load(ts+3, d0,d1, dv2, de);
    step(a0,a1, av, ae, ts);
    int n4 = (ts+4 < SEQ) ? ts+4 : SEQ-1;
    load(n4, a0,a1, av, ae);
    step(b0,b1, bv, be2, ts+1);
    int n5 = (ts+5 < SEQ) ? ts+5 : SEQ-1;
    load(n5, b0,b1, bv, be2);
    step(c0,c1, cv, ce, ts+2);
    int n6 = (ts+6 < SEQ) ? ts+6 : SEQ-1;
    load(n6, c0,c1, cv, ce);
    step(d0,d1, dv2, de, ts+3);
  }
}

// ---------------- gated RMSNorm -> bf16 ----------------
__global__ __launch_bounds__(128) void gatenorm_kernel(const float* __restrict__ outc, const ushort_t* __restrict__ qkvz,
                                                       const float* __restrict__ norm_w, ushort_t* __restrict__ gated){
  __shared__ float red[2];
  const int blk = blockIdx.x;
  const int nv = blk & 31;
  const size_t bt = (size_t)(blk >> 5);
  const int dv = threadIdx.x;
  float xv = outc[(bt*NV_ + nv)*(size_t)DV_ + dv];
  float ss = xv*xv;
  #pragma unroll
  for (int o=1;o<64;o<<=1) ss += __shfl_xor(ss, o);
  if ((threadIdx.x & 63)==0) red[threadIdx.x>>6] = ss;
  __syncthreads();
  float tot = red[0]+red[1];
  float xn = xv * rsqrtf(tot*(1.f/128.f) + 1e-6f) * norm_w[dv];
  int nk = nv>>1, r = nv&1;
  float z = bf2f(qkvz[bt*NQKVZ + nk*768 + 512 + r*128 + dv]);
  gated[bt*(size_t)4096 + nv*128 + dv] = f2bf(siluf_(z)*xn);
}

extern "C" void kernel_launch(void* const* d_in, const int* in_sizes, int n_in,
                              void* d_out, int out_size, void* d_ws, size_t ws_size,
                              hipStream_t stream){
  (void)in_sizes; (void)n_in; (void)out_size; (void)ws_size;
  const float* x      = (const float*)d_in[0];
  const float* W_qkvz = (const float*)d_in[1];
  const float* W_ba   = (const float*)d_in[2];
  const float* conv_w = (const float*)d_in[3];
  const float* dt_bias= (const float*)d_in[4];
  const float* A_log  = (const float*)d_in[5];
  const float* norm_w = (const float*)d_in[6];
  const float* W_out  = (const float*)d_in[7];
  float* outp = (float*)d_out;

  // ---- workspace layout (~238 MB, aliased; proven from rounds 3-5) ----
  char* w = (char*)d_ws;
  const size_t R0 = 0;                         // qkvz bf16: 100,663,296
  const size_t R1 = 100663296;                 // xb(16.8M)+wqt(50.3M) -> qkv bf16(67.1M) -> gated bf16(33.6M)
  const size_t R2 = R1 + 67108864;             // core fp32 (67.1M) -> wot bf16(16.8M)
  const size_t R3 = R2 + 67108864;             // smalls
  ushort_t* qkvz_bf = (ushort_t*)(w + R0);
  ushort_t* xb      = (ushort_t*)(w + R1);
  ushort_t* wqt     = (ushort_t*)(w + R1 + 16777216);
  ushort_t* qkv_bf  = (ushort_t*)(w + R1);
  ushort_t* gated   = (ushort_t*)(w + R1);
  float*    core    = (float*)   (w + R2);
  ushort_t* wot     = (ushort_t*)(w + R2);
  float*    ba      = (float*)   (w + R3);
  float2*   egb     = (float2*)  (w + R3 + 1048576);

  cast_x_kernel<<<(MTOT*HID/4 + 255)/256, 256, 0, stream>>>(x, xb, MTOT*HID/4);
  transpose_cast<<<dim3(NQKVZ/64, HID/64), 256, 0, stream>>>(W_qkvz, wqt, HID, NQKVZ);
  gemm_bf16<1><<<dim3(NQKVZ/128, MTOT/128), 256, 0, stream>>>(xb, wqt, (void*)qkvz_bf, MTOT, NQKVZ, HID);
  gemm_ba<<<MTOT/4, 256, 0, stream>>>(x, W_ba, ba);
  gbeta_kernel<<<(MTOT*NV_+255)/256, 256, 0, stream>>>(ba, A_log, dt_bias, egb);
  conv_norm_kernel<<<MTOT*64, 128, 0, stream>>>(qkvz_bf, conv_w, qkv_bf);
  recurrence_kernel<<<64*SPLIT, 256, 0, stream>>>(qkv_bf, egb, core);
  gatenorm_kernel<<<MTOT*NV_, 128, 0, stream>>>(core, qkvz_bf, norm_w, gated);
  transpose_cast<<<dim3(2048/64, 4096/64), 256, 0, stream>>>(W_out, wot, 4096, 2048);
  gemm_bf16<0><<<dim3(2048/128, MTOT/128), 256, 0, stream>>>(gated, wot, (void*)outp, MTOT, 2048, 4096);
}

// Round 7
// 1104.072 us; speedup vs baseline: 2.3718x; 1.1648x over previous
//
#include <hip/hip_runtime.h>
#include <stdint.h>

#define B_    2
#define SEQ   2048
#define HID   2048
#define NK_   16
#define NV_   32
#define DK_   128
#define DV_   128
#define NQKVZ 12288
#define CONVD 8192
#define MTOT  (B_*SEQ)   // 4096
#define CCH   16         // recurrence sub-chunk length

typedef unsigned short ushort_t;
typedef __bf16 bf16x8 __attribute__((ext_vector_type(8)));
typedef float  f32x4  __attribute__((ext_vector_type(4)));
typedef unsigned short us4 __attribute__((ext_vector_type(4)));

__device__ __forceinline__ ushort_t f2bf(float f){
  union { float f; unsigned u; } v; v.f = f;
  unsigned r = v.u + 0x7FFFu + ((v.u >> 16) & 1u);
  return (ushort_t)(r >> 16);
}
__device__ __forceinline__ float bf2f(ushort_t u){
  union { unsigned u; float f; } v; v.u = ((unsigned)u) << 16; return v.f;
}
__device__ __forceinline__ float sigmoidf_(float x){ return 1.f/(1.f+__expf(-x)); }
__device__ __forceinline__ float siluf_(float x){ return x*sigmoidf_(x); }

// ---------------- cast x -> bf16 ----------------
__global__ void cast_x_kernel(const float* __restrict__ x, ushort_t* __restrict__ xb, int n4){
  int i = blockIdx.x*256 + threadIdx.x;
  if (i >= n4) return;
  float4 v = ((const float4*)x)[i];
  us4 o; o[0]=f2bf(v.x); o[1]=f2bf(v.y); o[2]=f2bf(v.z); o[3]=f2bf(v.w);
  ((us4*)xb)[i] = o;
}

// ---------------- transpose + cast W[K][N] -> Wt[N][K] bf16 ----------------
__global__ __launch_bounds__(256) void transpose_cast(const float* __restrict__ W, ushort_t* __restrict__ Wt,
                                                      int K, int N){
  __shared__ float tile[64][65];
  int n0 = blockIdx.x*64, k0 = blockIdx.y*64;
  int tx = threadIdx.x & 63, ty = threadIdx.x >> 6;
  #pragma unroll
  for (int i=0;i<16;i++){
    int kr = ty + i*4;
    tile[kr][tx] = W[(size_t)(k0+kr)*N + n0+tx];
  }
  __syncthreads();
  #pragma unroll
  for (int i=0;i<16;i++){
    int nr = ty + i*4;
    Wt[(size_t)(n0+nr)*K + k0+tx] = f2bf(tile[tx][nr]);
  }
}

// ---------------- bf16 MFMA GEMM (global_load_lds staging) ----------------
template<int OUTBF>
__global__ __launch_bounds__(256) void gemm_bf16(const ushort_t* __restrict__ A, const ushort_t* __restrict__ Bt,
                                                 void* __restrict__ Cv, int M, int N, int K){
  __shared__ ushort_t As[128][32];
  __shared__ ushort_t Bs[128][32];
  const int t = threadIdx.x;
  const int lane = t & 63, w = t >> 6;
  const int wm = w >> 1, wn = w & 1;
  const int m0 = blockIdx.y * 128, n0 = blockIdx.x * 128;
  const int srow = lane >> 2;
  const int scol = (lane & 3) * 8;
  const ushort_t* gA0 = &A [(size_t)(m0 +      w*16 + srow)*K + scol];
  const ushort_t* gA1 = &A [(size_t)(m0 + 64 + w*16 + srow)*K + scol];
  const ushort_t* gB0 = &Bt[(size_t)(n0 +      w*16 + srow)*K + scol];
  const ushort_t* gB1 = &Bt[(size_t)(n0 + 64 + w*16 + srow)*K + scol];
  ushort_t* lA0 = &As[     w*16][0];
  ushort_t* lA1 = &As[64 + w*16][0];
  ushort_t* lB0 = &Bs[     w*16][0];
  ushort_t* lB1 = &Bs[64 + w*16][0];
  f32x4 acc[4][4];
  #pragma unroll
  for (int i=0;i<4;i++)
    #pragma unroll
    for (int j=0;j<4;j++) acc[i][j] = (f32x4){0.f,0.f,0.f,0.f};
  const int lr = lane & 15, lk = (lane >> 4) * 8;
  for (int k0 = 0; k0 < K; k0 += 32){
    __builtin_amdgcn_global_load_lds((const __attribute__((address_space(1))) void*)(gA0 + k0),
                                     (__attribute__((address_space(3))) void*)lA0, 16, 0, 0);
    __builtin_amdgcn_global_load_lds((const __attribute__((address_space(1))) void*)(gA1 + k0),
                                     (__attribute__((address_space(3))) void*)lA1, 16, 0, 0);
    __builtin_amdgcn_global_load_lds((const __attribute__((address_space(1))) void*)(gB0 + k0),
                                     (__attribute__((address_space(3))) void*)lB0, 16, 0, 0);
    __builtin_amdgcn_global_load_lds((const __attribute__((address_space(1))) void*)(gB1 + k0),
                                     (__attribute__((address_space(3))) void*)lB1, 16, 0, 0);
    __syncthreads();
    bf16x8 af[4], bfv[4];
    #pragma unroll
    for (int i=0;i<4;i++) af[i]  = *(const bf16x8*)&As[wm*64 + i*16 + lr][lk];
    #pragma unroll
    for (int j=0;j<4;j++) bfv[j] = *(const bf16x8*)&Bs[wn*64 + j*16 + lr][lk];
    #pragma unroll
    for (int i=0;i<4;i++)
      #pragma unroll
      for (int j=0;j<4;j++)
        acc[i][j] = __builtin_amdgcn_mfma_f32_16x16x32_bf16(af[i], bfv[j], acc[i][j], 0, 0, 0);
    __syncthreads();
  }
  const int lg = lane >> 4;
  #pragma unroll
  for (int i=0;i<4;i++)
    #pragma unroll
    for (int j=0;j<4;j++)
      #pragma unroll
      for (int r=0;r<4;r++){
        int m = m0 + wm*64 + i*16 + lg*4 + r;
        int n = n0 + wn*64 + j*16 + lr;
        if (OUTBF) ((ushort_t*)Cv)[(size_t)m*N + n] = f2bf(acc[i][j][r]);
        else       ((float*)Cv)[(size_t)m*N + n]    = acc[i][j][r];
      }
}

// ---------------- ba = x @ W_ba (fp32, N=64) ----------------
__global__ __launch_bounds__(256) void gemm_ba(const float* __restrict__ x, const float* __restrict__ Wba,
                                               float* __restrict__ ba){
  int lane = threadIdx.x & 63;
  int wid  = threadIdx.x >> 6;
  int row  = blockIdx.x*4 + wid;
  const float* xr = x + (size_t)row*HID;
  float acc = 0.f;
  for (int k=0;k<HID;k+=4){
    float4 xv = *(const float4*)&xr[k];
    acc += xv.x * Wba[(size_t)(k+0)*64 + lane];
    acc += xv.y * Wba[(size_t)(k+1)*64 + lane];
    acc += xv.z * Wba[(size_t)(k+2)*64 + lane];
    acc += xv.w * Wba[(size_t)(k+3)*64 + lane];
  }
  ba[(size_t)row*64 + lane] = acc;
}

// ---------------- conv(k=4) + SiLU + q/k RMS-norm (bf16 in/out) ----------------
__global__ __launch_bounds__(128) void conv_norm_kernel(const ushort_t* __restrict__ qkvz, const float* __restrict__ conv_w,
                                                        ushort_t* __restrict__ qkv){
  __shared__ float red[2];
  const int blk = blockIdx.x;
  const int gi = blk & 63;
  const int bt = blk >> 6;
  const int ts = bt & (SEQ-1);
  const int dk = threadIdx.x;
  int col;
  if (gi < 16)       col = gi*768 + dk;
  else if (gi < 32)  col = (gi-16)*768 + 128 + dk;
  else { int nv = gi-32; col = (nv>>1)*768 + 256 + (nv&1)*128 + dk; }
  const int c = gi*128 + dk;
  const float4 w = *(const float4*)&conv_w[(size_t)c*4];
  float a0 = (ts>=3) ? bf2f(qkvz[(size_t)(bt-3)*NQKVZ + col]) : 0.f;
  float a1 = (ts>=2) ? bf2f(qkvz[(size_t)(bt-2)*NQKVZ + col]) : 0.f;
  float a2 = (ts>=1) ? bf2f(qkvz[(size_t)(bt-1)*NQKVZ + col]) : 0.f;
  float a3 =           bf2f(qkvz[(size_t)(bt  )*NQKVZ + col]);
  float acc = a0*w.x + a1*w.y + a2*w.z + a3*w.w;
  float y = siluf_(acc);
  float outv = y;
  if (gi < 32){
    float ss = y*y;
    #pragma unroll
    for (int o=1;o<64;o<<=1) ss += __shfl_xor(ss, o);
    if ((threadIdx.x & 63) == 0) red[threadIdx.x>>6] = ss;
    __syncthreads();
    float tot = red[0] + red[1];
    float rs = rsqrtf(tot*(1.f/128.f) + 1e-6f);
    float scale = (gi < 16) ? (1.f/128.f) : 0.08838834764831845f;
    outv = y*rs*scale;
  }
  qkv[(size_t)bt*CONVD + gi*128 + dk] = f2bf(outv);
}

// ---------------- {g, beta} as float2 (g in LOG space for chunked prefix) ----------------
__global__ void gbeta_kernel(const float* __restrict__ ba, const float* __restrict__ A_log,
                             const float* __restrict__ dt_bias, float2* __restrict__ egb){
  int idx = blockIdx.x*256 + threadIdx.x;
  if (idx >= MTOT*NV_) return;
  int nv = idx & 31;
  int bt = idx >> 5;
  int nk = nv >> 1, r = nv & 1;
  float bg = ba[(size_t)bt*64 + nk*4 + r];
  float ag = ba[(size_t)bt*64 + nk*4 + 2 + r];
  float ad = ag + dt_bias[nv];
  float sp = fmaxf(ad, 0.f) + log1pf(__expf(-fabsf(ad)));
  float g  = -__expf(A_log[nv]) * sp;
  egb[idx] = make_float2(g, sigmoidf_(bg));
}

// ---------------- chunked gated delta-rule on MFMA ----------------
// grid = B*NV*2 = 128 blocks (head x dv-half), 512 threads = 8 waves.
// State kept as S^T [64 dv][128 dk] in MFMA C-layout regs: wave w owns dv-tile (w>>1),
// dk-tiles (w&1)*4..+3 -> 4 tiles x f32x4.
__global__ __launch_bounds__(512) void recurrence_chunked(const ushort_t* __restrict__ qkv,
                                                          const float2* __restrict__ egb,
                                                          float* __restrict__ outc){
  const int bi = blockIdx.x;
  const int b    = bi >> 6;
  const int nv   = (bi >> 1) & 31;
  const int half = bi & 1;
  const int nk   = nv >> 1;
  const int t    = threadIdx.x;
  const int lane = t & 63, w = t >> 6;
  const int lr   = lane & 15, hk = lane >> 4;

  __shared__ ushort_t Kl[16*136];       // K chunk rows (padded)
  __shared__ ushort_t Vl[16*72];        // V chunk (dv-half)
  __shared__ ushort_t S0h[64*136];      // S^T hi bf16
  __shared__ ushort_t S0l[64*136];      // S^T lo bf16
  __shared__ ushort_t KT[128*40];       // K' transposed [dk][t], k-padded (cols 16..31 zero)
  __shared__ ushort_t DT[64*40];        // Delta^T bf16 [dv][t], k-padded
  __shared__ ushort_t Wl[16*40];        // W bf16 [i][j], k-padded
  __shared__ float    Al[16*17];        // A f32
  __shared__ float    Ul[16*65];        // u f32
  __shared__ float    cl[16], bl[16], ksl[16], c15s[1];

  // zero-init (zero k-pad regions persist across iterations)
  for (int i = t; i < 64*40;  i += 512) DT[i] = 0;
  for (int i = t; i < 128*40; i += 512) KT[i] = 0;
  for (int i = t; i < 16*40;  i += 512) Wl[i] = 0;
  for (int i = t; i < 64*136; i += 512){ S0h[i] = 0; S0l[i] = 0; }

  f32x4 S[4];
  #pragma unroll
  for (int i=0;i<4;i++) S[i] = (f32x4){0.f,0.f,0.f,0.f};
  const int dt  = w >> 1;        // state dv-tile
  const int dkb = (w & 1) * 4;   // state dk-tile base

  const int st  = t >> 5, sdk = (t & 31) * 4;       // K staging coords
  const int vt  = (t & 255) >> 4, vdv = (t & 15)*4; // V staging coords (t<256)
  const size_t bt0 = (size_t)b*SEQ;
  const int mytile = (w < 4) ? w : (w - 4);

  for (int base = 0; base < SEQ; base += CCH){
    // ---- stage K,V to LDS; Q frags direct from global (waves 4-7) ----
    uint2 kstg = *(const uint2*)(qkv + (bt0+base+st)*CONVD + 2048 + nk*128 + sdk);
    uint2 vstg;
    if (t < 256) vstg = *(const uint2*)(qkv + (bt0+base+vt)*CONVD + 4096 + nv*128 + half*64 + vdv);
    bf16x8 qf[4];
    if (w >= 4){
      const ushort_t* qrow = qkv + (bt0+base+lr)*CONVD + nk*128 + hk*8;
      #pragma unroll
      for (int ks=0;ks<4;ks++) qf[ks] = *(const bf16x8*)(qrow + ks*32);
    }
    float2 gb = make_float2(0.f,0.f);
    if (w==0 && lane<16) gb = egb[(bt0+base+lane)*NV_ + nv];
    *(uint2*)&Kl[st*136 + sdk] = kstg;
    if (t < 256) *(uint2*)&Vl[vt*72 + vdv] = vstg;
    if (w==0 && lane<16){
      float c = gb.x;
      #pragma unroll
      for (int o=1;o<16;o<<=1){ float tv = __shfl_up(c, o, 16); if (lane >= o) c += tv; }
      cl[lane] = c; bl[lane] = gb.y;
      float c15 = __shfl(c, 15, 16);
      ksl[lane] = __expf(c15 - c);
      if (lane==0) c15s[0] = c15;
    }
    __syncthreads();   // B2: staging + prefix ready

    // ---- fragments + products ----
    bf16x8 kf[4];
    if (w <= 4){
      #pragma unroll
      for (int ks=0;ks<4;ks++) kf[ks] = *(const bf16x8*)&Kl[lr*136 + hk*8 + ks*32];
    }
    // KS0 (waves 0-3) / QS0 (waves 4-7), hi+lo
    f32x4 ph = (f32x4){0.f,0.f,0.f,0.f}, pl = ph;
    {
      #pragma unroll
      for (int ks=0;ks<4;ks++){
        bf16x8 xf = (w < 4) ? kf[ks] : qf[ks];
        bf16x8 yh = *(const bf16x8*)&S0h[(mytile*16+lr)*136 + hk*8 + ks*32];
        bf16x8 yl = *(const bf16x8*)&S0l[(mytile*16+lr)*136 + hk*8 + ks*32];
        ph = __builtin_amdgcn_mfma_f32_16x16x32_bf16(xf, yh, ph, 0,0,0);
        pl = __builtin_amdgcn_mfma_f32_16x16x32_bf16(xf, yl, pl, 0,0,0);
      }
    }
    if (w == 0){ // KK^T -> A
      f32x4 a = (f32x4){0.f,0.f,0.f,0.f};
      #pragma unroll
      for (int ks=0;ks<4;ks++) a = __builtin_amdgcn_mfma_f32_16x16x32_bf16(kf[ks], kf[ks], a, 0,0,0);
      #pragma unroll
      for (int r=0;r<4;r++){
        int i = hk*4 + r, j = lr;
        Al[i*17 + j] = (j < i) ? bl[i]*__expf(cl[i]-cl[j])*a[r] : 0.f;
      }
    }
    if (w == 4){ // QK^T -> W
      f32x4 a = (f32x4){0.f,0.f,0.f,0.f};
      #pragma unroll
      for (int ks=0;ks<4;ks++) a = __builtin_amdgcn_mfma_f32_16x16x32_bf16(qf[ks], kf[ks], a, 0,0,0);
      #pragma unroll
      for (int r=0;r<4;r++){
        int i = hk*4 + r, j = lr;
        float val = (j <= i) ? __expf(cl[i]-cl[j])*a[r] : 0.f;
        Wl[i*40 + j] = f2bf(val);
      }
    }
    if (w < 4){ // u = beta*(v - Gamma*KS0)
      #pragma unroll
      for (int r=0;r<4;r++){
        int i = hk*4 + r;
        float ks0 = ph[r] + pl[r];
        float vv = bf2f(Vl[i*72 + w*16 + lr]);
        Ul[i*65 + w*16 + lr] = bl[i]*(vv - __expf(cl[i])*ks0);
      }
    }
    if (w == 2 || w == 3){ // K' transpose build: K'[t][dk]=e^{c15-c_t}k_t -> KT[dk][t]
      int dk = t & 127;
      #pragma unroll
      for (int j=0;j<16;j+=2){
        unsigned p0 = f2bf(ksl[j]  * bf2f(Kl[j*136     + dk]));
        unsigned p1 = f2bf(ksl[j+1]* bf2f(Kl[(j+1)*136 + dk]));
        *(unsigned*)&KT[dk*40 + j] = p0 | (p1 << 16);
      }
    }
    __syncthreads();   // B3: A,u,KT,W ready

    if (w == 0){ // forward substitution (f32), write Delta^T bf16
      float d[16];
      #pragma unroll
      for (int r=0;r<16;r++) d[r] = Ul[r*65 + lane];
      #pragma unroll
      for (int r=1;r<16;r++){
        #pragma unroll
        for (int j=0;j<r;j++) d[r] -= Al[r*17 + j]*d[j];
      }
      unsigned dd[8];
      #pragma unroll
      for (int p=0;p<8;p++) dd[p] = (unsigned)f2bf(d[2*p]) | ((unsigned)f2bf(d[2*p+1]) << 16);
      *(uint4*)&DT[lane*40 + 0] = make_uint4(dd[0],dd[1],dd[2],dd[3]);
      *(uint4*)&DT[lane*40 + 8] = make_uint4(dd[4],dd[5],dd[6],dd[7]);
    }
    __syncthreads();   // B4: Delta ready

    if (w >= 4){ // O = W@Delta + Gamma*(QS0h+QS0l) -> global
      int ot = w - 4;
      bf16x8 wf = *(const bf16x8*)&Wl[lr*40 + hk*8];
      bf16x8 df = *(const bf16x8*)&DT[(ot*16+lr)*40 + hk*8];
      f32x4 oo = __builtin_amdgcn_mfma_f32_16x16x32_bf16(wf, df, (f32x4){0.f,0.f,0.f,0.f}, 0,0,0);
      #pragma unroll
      for (int r=0;r<4;r++){
        int i = hk*4 + r;
        float o = oo[r] + __expf(cl[i])*(ph[r] + pl[r]);
        outc[((bt0+base+i)*NV_ + nv)*(size_t)DV_ + half*64 + ot*16 + lr] = o;
      }
    }
    { // state update: S^T = e^{c15} S^T + Delta^T K'
      float g15 = __expf(c15s[0]);
      bf16x8 xf = *(const bf16x8*)&DT[(dt*16+lr)*40 + hk*8];
      #pragma unroll
      for (int tt=0;tt<4;tt++){
        bf16x8 yf = *(const bf16x8*)&KT[((dkb+tt)*16+lr)*40 + hk*8];
        f32x4 s = S[tt];
        s[0]*=g15; s[1]*=g15; s[2]*=g15; s[3]*=g15;
        S[tt] = __builtin_amdgcn_mfma_f32_16x16x32_bf16(xf, yf, s, 0,0,0);
      }
    }
    // write back S^T as bf16 hi/lo for next chunk's S0 products
    #pragma unroll
    for (int tt=0;tt<4;tt++){
      #pragma unroll
      for (int r=0;r<4;r++){
        int dvrow = dt*16 + hk*4 + r;
        int dkcol = (dkb+tt)*16 + lr;
        float sv = S[tt][r];
        ushort_t h = f2bf(sv);
        S0h[dvrow*136 + dkcol] = h;
        S0l[dvrow*136 + dkcol] = f2bf(sv - bf2f(h));
      }
    }
    __syncthreads();   // B5: S0 ready for next iteration
  }
}

// ---------------- gated RMSNorm -> bf16 ----------------
__global__ __launch_bounds__(128) void gatenorm_kernel(const float* __restrict__ outc, const ushort_t* __restrict__ qkvz,
                                                       const float* __restrict__ norm_w, ushort_t* __restrict__ gated){
  __shared__ float red[2];
  const int blk = blockIdx.x;
  const int nv = blk & 31;
  const size_t bt = (size_t)(blk >> 5);
  const int dv = threadIdx.x;
  float xv = outc[(bt*NV_ + nv)*(size_t)DV_ + dv];
  float ss = xv*xv;
  #pragma unroll
  for (int o=1;o<64;o<<=1) ss += __shfl_xor(ss, o);
  if ((threadIdx.x & 63)==0) red[threadIdx.x>>6] = ss;
  __syncthreads();
  float tot = red[0]+red[1];
  float xn = xv * rsqrtf(tot*(1.f/128.f) + 1e-6f) * norm_w[dv];
  int nk = nv>>1, r = nv&1;
  float z = bf2f(qkvz[bt*NQKVZ + nk*768 + 512 + r*128 + dv]);
  gated[bt*(size_t)4096 + nv*128 + dv] = f2bf(siluf_(z)*xn);
}

extern "C" void kernel_launch(void* const* d_in, const int* in_sizes, int n_in,
                              void* d_out, int out_size, void* d_ws, size_t ws_size,
                              hipStream_t stream){
  (void)in_sizes; (void)n_in; (void)out_size; (void)ws_size;
  const float* x      = (const float*)d_in[0];
  const float* W_qkvz = (const float*)d_in[1];
  const float* W_ba   = (const float*)d_in[2];
  const float* conv_w = (const float*)d_in[3];
  const float* dt_bias= (const float*)d_in[4];
  const float* A_log  = (const float*)d_in[5];
  const float* norm_w = (const float*)d_in[6];
  const float* W_out  = (const float*)d_in[7];
  float* outp = (float*)d_out;

  char* w = (char*)d_ws;
  const size_t R0 = 0;
  const size_t R1 = 100663296;
  const size_t R2 = R1 + 67108864;
  const size_t R3 = R2 + 67108864;
  ushort_t* qkvz_bf = (ushort_t*)(w + R0);
  ushort_t* xb      = (ushort_t*)(w + R1);
  ushort_t* wqt     = (ushort_t*)(w + R1 + 16777216);
  ushort_t* qkv_bf  = (ushort_t*)(w + R1);
  ushort_t* gated   = (ushort_t*)(w + R1);
  float*    core    = (float*)   (w + R2);
  ushort_t* wot     = (ushort_t*)(w + R2);
  float*    ba      = (float*)   (w + R3);
  float2*   egb     = (float2*)  (w + R3 + 1048576);

  cast_x_kernel<<<(MTOT*HID/4 + 255)/256, 256, 0, stream>>>(x, xb, MTOT*HID/4);
  transpose_cast<<<dim3(NQKVZ/64, HID/64), 256, 0, stream>>>(W_qkvz, wqt, HID, NQKVZ);
  gemm_bf16<1><<<dim3(NQKVZ/128, MTOT/128), 256, 0, stream>>>(xb, wqt, (void*)qkvz_bf, MTOT, NQKVZ, HID);
  gemm_ba<<<MTOT/4, 256, 0, stream>>>(x, W_ba, ba);
  gbeta_kernel<<<(MTOT*NV_+255)/256, 256, 0, stream>>>(ba, A_log, dt_bias, egb);
  conv_norm_kernel<<<MTOT*64, 128, 0, stream>>>(qkvz_bf, conv_w, qkv_bf);
  recurrence_chunked<<<B_*NV_*2, 512, 0, stream>>>(qkv_bf, egb, core);
  gatenorm_kernel<<<MTOT*NV_, 128, 0, stream>>>(core, qkvz_bf, norm_w, gated);
  transpose_cast<<<dim3(2048/64, 4096/64), 256, 0, stream>>>(W_out, wot, 4096, 2048);
  gemm_bf16<0><<<dim3(2048/128, MTOT/128), 256, 0, stream>>>(gated, wot, (void*)outp, MTOT, 2048, 4096);
}

// Round 8
// 1095.901 us; speedup vs baseline: 2.3895x; 1.0075x over previous
//
#include <hip/hip_runtime.h>
#include <stdint.h>

#define B_    2
#define SEQ   2048
#define HID   2048
#define NK_   16
#define NV_   32
#define DK_   128
#define DV_   128
#define NQKVZ 12288
#define CONVD 8192
#define MTOT  (B_*SEQ)   // 4096
#define CCH   16         // recurrence sub-chunk length

typedef unsigned short ushort_t;
typedef __bf16 bf16x8 __attribute__((ext_vector_type(8)));
typedef float  f32x4  __attribute__((ext_vector_type(4)));
typedef unsigned short us4 __attribute__((ext_vector_type(4)));

__device__ __forceinline__ ushort_t f2bf(float f){
  union { float f; unsigned u; } v; v.f = f;
  unsigned r = v.u + 0x7FFFu + ((v.u >> 16) & 1u);
  return (ushort_t)(r >> 16);
}
__device__ __forceinline__ float bf2f(ushort_t u){
  union { unsigned u; float f; } v; v.u = ((unsigned)u) << 16; return v.f;
}
__device__ __forceinline__ float sigmoidf_(float x){ return 1.f/(1.f+__expf(-x)); }
__device__ __forceinline__ float siluf_(float x){ return x*sigmoidf_(x); }

// ---------------- cast x -> bf16 ----------------
__global__ void cast_x_kernel(const float* __restrict__ x, ushort_t* __restrict__ xb, int n4){
  int i = blockIdx.x*256 + threadIdx.x;
  if (i >= n4) return;
  float4 v = ((const float4*)x)[i];
  us4 o; o[0]=f2bf(v.x); o[1]=f2bf(v.y); o[2]=f2bf(v.z); o[3]=f2bf(v.w);
  ((us4*)xb)[i] = o;
}

// ---------------- transpose + cast W[K][N] -> Wt[N][K] bf16 ----------------
__global__ __launch_bounds__(256) void transpose_cast(const float* __restrict__ W, ushort_t* __restrict__ Wt,
                                                      int K, int N){
  __shared__ float tile[64][65];
  int n0 = blockIdx.x*64, k0 = blockIdx.y*64;
  int tx = threadIdx.x & 63, ty = threadIdx.x >> 6;
  #pragma unroll
  for (int i=0;i<16;i++){
    int kr = ty + i*4;
    tile[kr][tx] = W[(size_t)(k0+kr)*N + n0+tx];
  }
  __syncthreads();
  #pragma unroll
  for (int i=0;i<16;i++){
    int nr = ty + i*4;
    Wt[(size_t)(n0+nr)*K + k0+tx] = f2bf(tile[tx][nr]);
  }
}

// ---------------- bf16 MFMA GEMM (global_load_lds staging) ----------------
template<int OUTBF>
__global__ __launch_bounds__(256) void gemm_bf16(const ushort_t* __restrict__ A, const ushort_t* __restrict__ Bt,
                                                 void* __restrict__ Cv, int M, int N, int K){
  __shared__ ushort_t As[128][32];
  __shared__ ushort_t Bs[128][32];
  const int t = threadIdx.x;
  const int lane = t & 63, w = t >> 6;
  const int wm = w >> 1, wn = w & 1;
  const int m0 = blockIdx.y * 128, n0 = blockIdx.x * 128;
  const int srow = lane >> 2;
  const int scol = (lane & 3) * 8;
  const ushort_t* gA0 = &A [(size_t)(m0 +      w*16 + srow)*K + scol];
  const ushort_t* gA1 = &A [(size_t)(m0 + 64 + w*16 + srow)*K + scol];
  const ushort_t* gB0 = &Bt[(size_t)(n0 +      w*16 + srow)*K + scol];
  const ushort_t* gB1 = &Bt[(size_t)(n0 + 64 + w*16 + srow)*K + scol];
  ushort_t* lA0 = &As[     w*16][0];
  ushort_t* lA1 = &As[64 + w*16][0];
  ushort_t* lB0 = &Bs[     w*16][0];
  ushort_t* lB1 = &Bs[64 + w*16][0];
  f32x4 acc[4][4];
  #pragma unroll
  for (int i=0;i<4;i++)
    #pragma unroll
    for (int j=0;j<4;j++) acc[i][j] = (f32x4){0.f,0.f,0.f,0.f};
  const int lr = lane & 15, lk = (lane >> 4) * 8;
  for (int k0 = 0; k0 < K; k0 += 32){
    __builtin_amdgcn_global_load_lds((const __attribute__((address_space(1))) void*)(gA0 + k0),
                                     (__attribute__((address_space(3))) void*)lA0, 16, 0, 0);
    __builtin_amdgcn_global_load_lds((const __attribute__((address_space(1))) void*)(gA1 + k0),
                                     (__attribute__((address_space(3))) void*)lA1, 16, 0, 0);
    __builtin_amdgcn_global_load_lds((const __attribute__((address_space(1))) void*)(gB0 + k0),
                                     (__attribute__((address_space(3))) void*)lB0, 16, 0, 0);
    __builtin_amdgcn_global_load_lds((const __attribute__((address_space(1))) void*)(gB1 + k0),
                                     (__attribute__((address_space(3))) void*)lB1, 16, 0, 0);
    __syncthreads();
    bf16x8 af[4], bfv[4];
    #pragma unroll
    for (int i=0;i<4;i++) af[i]  = *(const bf16x8*)&As[wm*64 + i*16 + lr][lk];
    #pragma unroll
    for (int j=0;j<4;j++) bfv[j] = *(const bf16x8*)&Bs[wn*64 + j*16 + lr][lk];
    #pragma unroll
    for (int i=0;i<4;i++)
      #pragma unroll
      for (int j=0;j<4;j++)
        acc[i][j] = __builtin_amdgcn_mfma_f32_16x16x32_bf16(af[i], bfv[j], acc[i][j], 0, 0, 0);
    __syncthreads();
  }
  const int lg = lane >> 4;
  #pragma unroll
  for (int i=0;i<4;i++)
    #pragma unroll
    for (int j=0;j<4;j++)
      #pragma unroll
      for (int r=0;r<4;r++){
        int m = m0 + wm*64 + i*16 + lg*4 + r;
        int n = n0 + wn*64 + j*16 + lr;
        if (OUTBF) ((ushort_t*)Cv)[(size_t)m*N + n] = f2bf(acc[i][j][r]);
        else       ((float*)Cv)[(size_t)m*N + n]    = acc[i][j][r];
      }
}

// ---------------- ba = x @ W_ba (fp32, N=64) ----------------
__global__ __launch_bounds__(256) void gemm_ba(const float* __restrict__ x, const float* __restrict__ Wba,
                                               float* __restrict__ ba){
  int lane = threadIdx.x & 63;
  int wid  = threadIdx.x >> 6;
  int row  = blockIdx.x*4 + wid;
  const float* xr = x + (size_t)row*HID;
  float acc = 0.f;
  for (int k=0;k<HID;k+=4){
    float4 xv = *(const float4*)&xr[k];
    acc += xv.x * Wba[(size_t)(k+0)*64 + lane];
    acc += xv.y * Wba[(size_t)(k+1)*64 + lane];
    acc += xv.z * Wba[(size_t)(k+2)*64 + lane];
    acc += xv.w * Wba[(size_t)(k+3)*64 + lane];
  }
  ba[(size_t)row*64 + lane] = acc;
}

// ---------------- conv(k=4) + SiLU + q/k RMS-norm (bf16 in/out) ----------------
__global__ __launch_bounds__(128) void conv_norm_kernel(const ushort_t* __restrict__ qkvz, const float* __restrict__ conv_w,
                                                        ushort_t* __restrict__ qkv){
  __shared__ float red[2];
  const int blk = blockIdx.x;
  const int gi = blk & 63;
  const int bt = blk >> 6;
  const int ts = bt & (SEQ-1);
  const int dk = threadIdx.x;
  int col;
  if (gi < 16)       col = gi*768 + dk;
  else if (gi < 32)  col = (gi-16)*768 + 128 + dk;
  else { int nv = gi-32; col = (nv>>1)*768 + 256 + (nv&1)*128 + dk; }
  const int c = gi*128 + dk;
  const float4 w = *(const float4*)&conv_w[(size_t)c*4];
  float a0 = (ts>=3) ? bf2f(qkvz[(size_t)(bt-3)*NQKVZ + col]) : 0.f;
  float a1 = (ts>=2) ? bf2f(qkvz[(size_t)(bt-2)*NQKVZ + col]) : 0.f;
  float a2 = (ts>=1) ? bf2f(qkvz[(size_t)(bt-1)*NQKVZ + col]) : 0.f;
  float a3 =           bf2f(qkvz[(size_t)(bt  )*NQKVZ + col]);
  float acc = a0*w.x + a1*w.y + a2*w.z + a3*w.w;
  float y = siluf_(acc);
  float outv = y;
  if (gi < 32){
    float ss = y*y;
    #pragma unroll
    for (int o=1;o<64;o<<=1) ss += __shfl_xor(ss, o);
    if ((threadIdx.x & 63) == 0) red[threadIdx.x>>6] = ss;
    __syncthreads();
    float tot = red[0] + red[1];
    float rs = rsqrtf(tot*(1.f/128.f) + 1e-6f);
    float scale = (gi < 16) ? (1.f/128.f) : 0.08838834764831845f;
    outv = y*rs*scale;
  }
  qkv[(size_t)bt*CONVD + gi*128 + dk] = f2bf(outv);
}

// ---------------- {g, beta} as float2 (g in LOG space) ----------------
__global__ void gbeta_kernel(const float* __restrict__ ba, const float* __restrict__ A_log,
                             const float* __restrict__ dt_bias, float2* __restrict__ egb){
  int idx = blockIdx.x*256 + threadIdx.x;
  if (idx >= MTOT*NV_) return;
  int nv = idx & 31;
  int bt = idx >> 5;
  int nk = nv >> 1, r = nv & 1;
  float bg = ba[(size_t)bt*64 + nk*4 + r];
  float ag = ba[(size_t)bt*64 + nk*4 + 2 + r];
  float ad = ag + dt_bias[nv];
  float sp = fmaxf(ad, 0.f) + log1pf(__expf(-fabsf(ad)));
  float g  = -__expf(A_log[nv]) * sp;
  egb[idx] = make_float2(g, sigmoidf_(bg));
}

// ---------------- chunked gated delta-rule on MFMA, software-pipelined ----------------
// grid = B*NV*2 = 128 blocks (head x dv-half), 512 threads = 8 waves.
// 3 phases, 3 barriers per chunk; next-chunk K/V/Q/egb prefetched into regs during phase2/3.
__global__ __launch_bounds__(512) void recurrence_chunked(const ushort_t* __restrict__ qkv,
                                                          const float2* __restrict__ egb,
                                                          float* __restrict__ outc){
  const int bi = blockIdx.x;
  const int b    = bi >> 6;
  const int nv   = (bi >> 1) & 31;
  const int half = bi & 1;
  const int nk   = nv >> 1;
  const int t    = threadIdx.x;
  const int lane = t & 63, w = t >> 6;
  const int lr   = lane & 15, hk = lane >> 4;

  __shared__ ushort_t Kl[16*136];
  __shared__ ushort_t S0h[64*136];
  __shared__ ushort_t S0l[64*136];
  __shared__ ushort_t KT[128*40];
  __shared__ ushort_t DT[64*40];
  __shared__ ushort_t Wl[16*40];
  __shared__ float    Al[16*20];        // 16B-aligned rows for float4 reads
  __shared__ float    Ul[16*65];
  __shared__ float    clB[2][16], blB[2][16], eclB[2][16], kslB[2][16], c15B[2];

  // one-time zero init (k-pad regions persist)
  for (int i = t; i < 64*40;  i += 512) DT[i] = 0;
  for (int i = t; i < 128*40; i += 512) KT[i] = 0;
  for (int i = t; i < 16*40;  i += 512) Wl[i] = 0;
  for (int i = t; i < 64*136; i += 512){ S0h[i] = 0; S0l[i] = 0; }

  f32x4 S[4];
  #pragma unroll
  for (int i=0;i<4;i++) S[i] = (f32x4){0.f,0.f,0.f,0.f};
  const int dt  = w >> 1;
  const int dkb = (w & 1) * 4;
  const int ot  = w - 4;                // output dv-tile for w>=4
  const int st  = t >> 5, sdk = (t & 31) * 4;
  const size_t bt0 = (size_t)b*SEQ;
  const int mytile = (w < 4) ? w : (w - 4);

  // -------- prologue: load chunk 0 into regs, stage, prefix --------
  uint2 kreg = *(const uint2*)(qkv + (bt0+st)*CONVD + 2048 + nk*128 + sdk);
  bf16x8 qf[4];
  if (w >= 4){
    const ushort_t* qrow = qkv + (bt0+lr)*CONVD + nk*128 + hk*8;
    #pragma unroll
    for (int ks=0;ks<4;ks++) qf[ks] = *(const bf16x8*)(qrow + ks*32);
  }
  ushort_t vreg[4];
  if (w < 4){
    #pragma unroll
    for (int r=0;r<4;r++)
      vreg[r] = qkv[(bt0+hk*4+r)*CONVD + 4096 + nv*128 + half*64 + w*16 + lr];
  }
  {
    float2 gb = make_float2(0.f,0.f);
    if (w==1 && lane<16) gb = egb[(bt0+lane)*NV_ + nv];
    *(uint2*)&Kl[st*136 + sdk] = kreg;
    if (w==1 && lane<16){
      float c = gb.x;
      #pragma unroll
      for (int o=1;o<16;o<<=1){ float tv = __shfl_up(c, o, 16); if (lane >= o) c += tv; }
      clB[0][lane] = c; blB[0][lane] = gb.y; eclB[0][lane] = __expf(c);
      float c15 = __shfl(c, 15, 16);
      kslB[0][lane] = __expf(c15 - c);
      if (lane==0) c15B[0] = c15;
    }
  }
  __syncthreads();

  int pb = 0;
  for (int base = 0; base < SEQ; base += CCH){
    const int nbase = (base + CCH < SEQ) ? base + CCH : base;

    // ================= phase 1: products + A/W/u/KT builds =================
    bf16x8 kf[4];
    if (w <= 4){
      #pragma unroll
      for (int ks=0;ks<4;ks++) kf[ks] = *(const bf16x8*)&Kl[lr*136 + hk*8 + ks*32];
    }
    f32x4 ph = (f32x4){0.f,0.f,0.f,0.f}, pl = ph;
    #pragma unroll
    for (int ks=0;ks<4;ks++){
      bf16x8 xf = (w < 4) ? kf[ks] : qf[ks];
      bf16x8 yh = *(const bf16x8*)&S0h[(mytile*16+lr)*136 + hk*8 + ks*32];
      bf16x8 yl = *(const bf16x8*)&S0l[(mytile*16+lr)*136 + hk*8 + ks*32];
      ph = __builtin_amdgcn_mfma_f32_16x16x32_bf16(xf, yh, ph, 0,0,0);
      pl = __builtin_amdgcn_mfma_f32_16x16x32_bf16(xf, yl, pl, 0,0,0);
    }
    if (w == 1){ // A build
      f32x4 a = (f32x4){0.f,0.f,0.f,0.f};
      #pragma unroll
      for (int ks=0;ks<4;ks++) a = __builtin_amdgcn_mfma_f32_16x16x32_bf16(kf[ks], kf[ks], a, 0,0,0);
      #pragma unroll
      for (int r=0;r<4;r++){
        int i = hk*4 + r, j = lr;
        Al[i*20 + j] = (j < i) ? blB[pb][i]*__expf(clB[pb][i]-clB[pb][j])*a[r] : 0.f;
      }
    }
    if (w == 4){ // W build
      f32x4 a = (f32x4){0.f,0.f,0.f,0.f};
      #pragma unroll
      for (int ks=0;ks<4;ks++) a = __builtin_amdgcn_mfma_f32_16x16x32_bf16(qf[ks], kf[ks], a, 0,0,0);
      #pragma unroll
      for (int r=0;r<4;r++){
        int i = hk*4 + r, j = lr;
        float val = (j <= i) ? __expf(clB[pb][i]-clB[pb][j])*a[r] : 0.f;
        Wl[i*40 + j] = f2bf(val);
      }
    }
    if (w < 4){ // u build (v from prefetched regs)
      #pragma unroll
      for (int r=0;r<4;r++){
        int i = hk*4 + r;
        Ul[i*65 + w*16 + lr] = blB[pb][i]*(bf2f(vreg[r]) - eclB[pb][i]*(ph[r] + pl[r]));
      }
    }
    if (w == 2 || w == 3){ // K'^T build
      int dk = t & 127;
      #pragma unroll
      for (int j=0;j<16;j+=2){
        unsigned p0 = f2bf(kslB[pb][j]  * bf2f(Kl[j*136     + dk]));
        unsigned p1 = f2bf(kslB[pb][j+1]* bf2f(Kl[(j+1)*136 + dk]));
        *(unsigned*)&KT[dk*40 + j] = p0 | (p1 << 16);
      }
    }
    __syncthreads();   // B3: A,W,u,KT ready

    // ================= phase 2: substitution (w0) || prefetch next (others) =================
    kreg = *(const uint2*)(qkv + (bt0+nbase+st)*CONVD + 2048 + nk*128 + sdk);
    if (w >= 4){
      const ushort_t* qrow = qkv + (bt0+nbase+lr)*CONVD + nk*128 + hk*8;
      #pragma unroll
      for (int ks=0;ks<4;ks++) qf[ks] = *(const bf16x8*)(qrow + ks*32);
    }
    if (w < 4){
      #pragma unroll
      for (int r=0;r<4;r++)
        vreg[r] = qkv[(bt0+nbase+hk*4+r)*CONVD + 4096 + nv*128 + half*64 + w*16 + lr];
    }
    float2 ebn = make_float2(0.f,0.f);
    if (w==1 && lane<16) ebn = egb[(bt0+nbase+lane)*NV_ + nv];
    // pre-read fragments consumed in phase 3
    bf16x8 yf[4];
    #pragma unroll
    for (int tt=0;tt<4;tt++) yf[tt] = *(const bf16x8*)&KT[((dkb+tt)*16+lr)*40 + hk*8];
    bf16x8 wfr;
    if (w >= 4) wfr = *(const bf16x8*)&Wl[lr*40 + hk*8];

    if (w == 0){ // blocked forward substitution, column = lane
      float d[16];
      #pragma unroll
      for (int r=0;r<16;r++) d[r] = Ul[r*65 + lane];
      #pragma unroll
      for (int rb=0;rb<4;rb++){
        float p0=0.f,p1=0.f,p2=0.f,p3=0.f;
        #pragma unroll
        for (int jb=0;jb<rb;jb++){
          float4 A0 = *(const float4*)&Al[(rb*4+0)*20 + jb*4];
          float4 A1 = *(const float4*)&Al[(rb*4+1)*20 + jb*4];
          float4 A2 = *(const float4*)&Al[(rb*4+2)*20 + jb*4];
          float4 A3 = *(const float4*)&Al[(rb*4+3)*20 + jb*4];
          p0 += A0.x*d[jb*4]+A0.y*d[jb*4+1]+A0.z*d[jb*4+2]+A0.w*d[jb*4+3];
          p1 += A1.x*d[jb*4]+A1.y*d[jb*4+1]+A1.z*d[jb*4+2]+A1.w*d[jb*4+3];
          p2 += A2.x*d[jb*4]+A2.y*d[jb*4+1]+A2.z*d[jb*4+2]+A2.w*d[jb*4+3];
          p3 += A3.x*d[jb*4]+A3.y*d[jb*4+1]+A3.z*d[jb*4+2]+A3.w*d[jb*4+3];
        }
        const int r0 = rb*4;
        d[r0+0] -= p0;
        d[r0+1] -= p1 + Al[(r0+1)*20+r0]*d[r0];
        d[r0+2] -= p2 + Al[(r0+2)*20+r0]*d[r0] + Al[(r0+2)*20+r0+1]*d[r0+1];
        d[r0+3] -= p3 + Al[(r0+3)*20+r0]*d[r0] + Al[(r0+3)*20+r0+1]*d[r0+1] + Al[(r0+3)*20+r0+2]*d[r0+2];
      }
      unsigned dd[8];
      #pragma unroll
      for (int p=0;p<8;p++) dd[p] = (unsigned)f2bf(d[2*p]) | ((unsigned)f2bf(d[2*p+1]) << 16);
      *(uint4*)&DT[lane*40 + 0] = make_uint4(dd[0],dd[1],dd[2],dd[3]);
      *(uint4*)&DT[lane*40 + 8] = make_uint4(dd[4],dd[5],dd[6],dd[7]);
    }
    __syncthreads();   // B4: Delta ready

    // ================= phase 3: O + state update + writebacks + next staging =================
    if (w >= 4){
      bf16x8 dfr = *(const bf16x8*)&DT[(ot*16+lr)*40 + hk*8];
      f32x4 oo = __builtin_amdgcn_mfma_f32_16x16x32_bf16(wfr, dfr, (f32x4){0.f,0.f,0.f,0.f}, 0,0,0);
      #pragma unroll
      for (int r=0;r<4;r++){
        int i = hk*4 + r;
        outc[((bt0+base+i)*NV_ + nv)*(size_t)DV_ + half*64 + ot*16 + lr] = oo[r] + eclB[pb][i]*(ph[r] + pl[r]);
      }
    }
    {
      float g15 = __expf(c15B[pb]);
      bf16x8 xf2 = *(const bf16x8*)&DT[(dt*16+lr)*40 + hk*8];
      #pragma unroll
      for (int tt=0;tt<4;tt++){
        f32x4 s = S[tt];
        s[0]*=g15; s[1]*=g15; s[2]*=g15; s[3]*=g15;
        S[tt] = __builtin_amdgcn_mfma_f32_16x16x32_bf16(xf2, yf[tt], s, 0,0,0);
      }
    }
    #pragma unroll
    for (int tt=0;tt<4;tt++){
      #pragma unroll
      for (int r=0;r<4;r++){
        int dvrow = dt*16 + hk*4 + r;
        int dkcol = (dkb+tt)*16 + lr;
        float sv = S[tt][r];
        ushort_t h = f2bf(sv);
        S0h[dvrow*136 + dkcol] = h;
        S0l[dvrow*136 + dkcol] = f2bf(sv - bf2f(h));
      }
    }
    *(uint2*)&Kl[st*136 + sdk] = kreg;   // stage next chunk's K
    if (w==1 && lane<16){                 // next chunk's prefix
      float c = ebn.x;
      #pragma unroll
      for (int o=1;o<16;o<<=1){ float tv = __shfl_up(c, o, 16); if (lane >= o) c += tv; }
      clB[pb^1][lane] = c; blB[pb^1][lane] = ebn.y; eclB[pb^1][lane] = __expf(c);
      float c15 = __shfl(c, 15, 16);
      kslB[pb^1][lane] = __expf(c15 - c);
      if (lane==0) c15B[pb^1] = c15;
    }
    __syncthreads();   // B5: S0/Kl/prefix ready for next chunk
    pb ^= 1;
  }
}

// ---------------- gated RMSNorm -> bf16 ----------------
__global__ __launch_bounds__(128) void gatenorm_kernel(const float* __restrict__ outc, const ushort_t* __restrict__ qkvz,
                                                       const float* __restrict__ norm_w, ushort_t* __restrict__ gated){
  __shared__ float red[2];
  const int blk = blockIdx.x;
  const int nv = blk & 31;
  const size_t bt = (size_t)(blk >> 5);
  const int dv = threadIdx.x;
  float xv = outc[(bt*NV_ + nv)*(size_t)DV_ + dv];
  float ss = xv*xv;
  #pragma unroll
  for (int o=1;o<64;o<<=1) ss += __shfl_xor(ss, o);
  if ((threadIdx.x & 63)==0) red[threadIdx.x>>6] = ss;
  __syncthreads();
  float tot = red[0]+red[1];
  float xn = xv * rsqrtf(tot*(1.f/128.f) + 1e-6f) * norm_w[dv];
  int nk = nv>>1, r = nv&1;
  float z = bf2f(qkvz[bt*NQKVZ + nk*768 + 512 + r*128 + dv]);
  gated[bt*(size_t)4096 + nv*128 + dv] = f2bf(siluf_(z)*xn);
}

extern "C" void kernel_launch(void* const* d_in, const int* in_sizes, int n_in,
                              void* d_out, int out_size, void* d_ws, size_t ws_size,
                              hipStream_t stream){
  (void)in_sizes; (void)n_in; (void)out_size; (void)ws_size;
  const float* x      = (const float*)d_in[0];
  const float* W_qkvz = (const float*)d_in[1];
  const float* W_ba   = (const float*)d_in[2];
  const float* conv_w = (const float*)d_in[3];
  const float* dt_bias= (const float*)d_in[4];
  const float* A_log  = (const float*)d_in[5];
  const float* norm_w = (const float*)d_in[6];
  const float* W_out  = (const float*)d_in[7];
  float* outp = (float*)d_out;

  char* w = (char*)d_ws;
  const size_t R0 = 0;
  const size_t R1 = 100663296;
  const size_t R2 = R1 + 67108864;
  const size_t R3 = R2 + 67108864;
  ushort_t* qkvz_bf = (ushort_t*)(w + R0);
  ushort_t* xb      = (ushort_t*)(w + R1);
  ushort_t* wqt     = (ushort_t*)(w + R1 + 16777216);
  ushort_t* qkv_bf  = (ushort_t*)(w + R1);
  ushort_t* gated   = (ushort_t*)(w + R1);
  float*    core    = (float*)   (w + R2);
  ushort_t* wot     = (ushort_t*)(w + R2);
  float*    ba      = (float*)   (w + R3);
  float2*   egb     = (float2*)  (w + R3 + 1048576);

  cast_x_kernel<<<(MTOT*HID/4 + 255)/256, 256, 0, stream>>>(x, xb, MTOT*HID/4);
  transpose_cast<<<dim3(NQKVZ/64, HID/64), 256, 0, stream>>>(W_qkvz, wqt, HID, NQKVZ);
  gemm_bf16<1><<<dim3(NQKVZ/128, MTOT/128), 256, 0, stream>>>(xb, wqt, (void*)qkvz_bf, MTOT, NQKVZ, HID);
  gemm_ba<<<MTOT/4, 256, 0, stream>>>(x, W_ba, ba);
  gbeta_kernel<<<(MTOT*NV_+255)/256, 256, 0, stream>>>(ba, A_log, dt_bias, egb);
  conv_norm_kernel<<<MTOT*64, 128, 0, stream>>>(qkvz_bf, conv_w, qkv_bf);
  recurrence_chunked<<<B_*NV_*2, 512, 0, stream>>>(qkv_bf, egb, core);
  gatenorm_kernel<<<MTOT*NV_, 128, 0, stream>>>(core, qkvz_bf, norm_w, gated);
  transpose_cast<<<dim3(2048/64, 4096/64), 256, 0, stream>>>(W_out, wot, 4096, 2048);
  gemm_bf16<0><<<dim3(2048/128, MTOT/128), 256, 0, stream>>>(gated, wot, (void*)outp, MTOT, 2048, 4096);
}